// Round 20
// baseline (124.545 us; speedup 1.0000x reference)
//
#include <hip/hip_runtime.h>
#include <math.h>

#define B_ 2
#define T_ 2
#define H_ 28
#define W_ 28
#define S_ (H_*W_)      /* 784  */
#define L_ (T_*S_)      /* 1568 */
#define C_ 768
#define NH_ 12
#define HD_ 64
#define LN_EPS 1e-5f
#define LOG2E 1.4426950408889634f
#define SCALE_K (0.125f * LOG2E)   /* hd^-0.5 * log2e folded into K' */

typedef unsigned int uint_;
typedef unsigned int u32x2 __attribute__((ext_vector_type(2)));
typedef unsigned int u32x4 __attribute__((ext_vector_type(4)));
typedef __bf16 bf16x8 __attribute__((ext_vector_type(8)));
typedef float f32x4 __attribute__((ext_vector_type(4)));
typedef float f32x16 __attribute__((ext_vector_type(16)));

#define BC8(x) __builtin_bit_cast(bf16x8, (x))

__device__ __forceinline__ unsigned short f2bf(float f) {
  uint_ u = __builtin_bit_cast(uint_, f);
  u += 0x7FFFu + ((u >> 16) & 1u);
  return (unsigned short)(u >> 16);
}
__device__ __forceinline__ float bf2f(unsigned short h) {
  return __builtin_bit_cast(float, ((uint_)h) << 16);
}
__device__ __forceinline__ uint_ cvtpk(float a, float b) {
  uint_ r;
  asm("v_cvt_pk_bf16_f32 %0, %1, %2" : "=v"(r) : "v"(a), "v"(b));
  return r;
}
__device__ __forceinline__ void gload16(const void* g, void* l) {
  __builtin_amdgcn_global_load_lds(
      (const __attribute__((address_space(1))) unsigned int*)g,
      (__attribute__((address_space(3))) unsigned int*)l, 16, 0, 0);
}

// ---------------------------------------------------------------------------
// Fused f32 -> bf16 convert for x / qkv_w / out_w (range-dispatched)
// ---------------------------------------------------------------------------
__global__ __launch_bounds__(256) void cvt_all(
    const float* __restrict__ s0, int n0, unsigned short* __restrict__ d0,
    const float* __restrict__ s1, int n1, unsigned short* __restrict__ d1,
    const float* __restrict__ s2, int n2, unsigned short* __restrict__ d2) {
  int i = (blockIdx.x * 256 + threadIdx.x) * 8;
  const float* s; unsigned short* d;
  if (i < n0) { s = s0; d = d0; }
  else if (i < n0 + n1) { i -= n0; s = s1; d = d1; }
  else { i -= n0 + n1; if (i >= n2) return; s = s2; d = d2; }
  float4 a = *(const float4*)(s + i);
  float4 b = *(const float4*)(s + i + 4);
  u32x4 o;
  o.x = cvtpk(a.x, a.y); o.y = cvtpk(a.z, a.w);
  o.z = cvtpk(b.x, b.y); o.w = cvtpk(b.z, b.w);
  *(u32x4*)(d + i) = o;
}

// ---------------------------------------------------------------------------
// rel-pos tables -> bf16, LOG2E folded, padded to [64][64]
// ---------------------------------------------------------------------------
__global__ __launch_bounds__(256) void cvt_rel(
    const float* __restrict__ rph, const float* __restrict__ rpw,
    unsigned short* __restrict__ Rhb, unsigned short* __restrict__ Rwb) {
  const int i = blockIdx.x * 256 + threadIdx.x;   // 0..4095
  if (i >= 4096) return;
  const int j = i >> 6;
  const unsigned short vh = (j < 2*H_-1) ? f2bf(rph[i] * LOG2E) : 0;
  const unsigned short vw = (j < 2*W_-1) ? f2bf(rpw[i] * LOG2E) : 0;
  Rhb[i] = vh;
  Rwb[i] = vw;
}

// ---------------------------------------------------------------------------
// Templated bf16 MFMA GEMM core: C = A * B^T, BMxBN tile, BK=32, 4 waves
// (2x2), wave covers (BM/2)x(BN/2). Single-buffered LDS, 2 barriers/K-step.
// ---------------------------------------------------------------------------
template<int BM, int BN>
__device__ __forceinline__ void gemm_core_t(
    const unsigned short* __restrict__ A, const unsigned short* __restrict__ Bm,
    int K, int m0, int n0, f32x4 (&acc)[BM/32][BN/32]) {
  constexpr int MF = BM / 32;
  constexpr int NF = BN / 32;
  __shared__ __align__(16) unsigned short As[BM * 32];
  __shared__ __align__(16) unsigned short Bs[BN * 32];
  const int tid = threadIdx.x;
  const int lane = tid & 63;
  const int wv = tid >> 6;
  const int wm = wv >> 1, wn = wv & 1;
  const int srow = tid >> 2, scol = (tid & 3) * 8;
  const int fr = lane & 15, fk = (lane >> 4) * 8;
  const unsigned short* ag = A + (size_t)(m0 + srow) * K + scol;
  const unsigned short* bg = Bm + (size_t)(n0 + srow) * K + scol;
  unsigned short* asd = As + tid * 8;
  unsigned short* bsd = Bs + tid * 8;
  const int arow = wm * (BM / 2) + fr;
  const int brow = wn * (BN / 2) + fr;
  for (int k0 = 0; k0 < K; k0 += 32) {
    __syncthreads();
    #pragma unroll
    for (int r = 0; r < BM / 64; ++r)
      gload16(ag + (size_t)(r * 64) * K + k0, asd + r * 2048);
    #pragma unroll
    for (int r = 0; r < BN / 64; ++r)
      gload16(bg + (size_t)(r * 64) * K + k0, bsd + r * 2048);
    __syncthreads();
    bf16x8 af[MF], bfr[NF];
    #pragma unroll
    for (int m = 0; m < MF; ++m)
      af[m] = *(const bf16x8*)(As + (arow + m * 16) * 32 + fk);
    #pragma unroll
    for (int n = 0; n < NF; ++n)
      bfr[n] = *(const bf16x8*)(Bs + (brow + n * 16) * 32 + fk);
    #pragma unroll
    for (int m = 0; m < MF; ++m)
      #pragma unroll
      for (int n = 0; n < NF; ++n)
        acc[m][n] = __builtin_amdgcn_mfma_f32_16x16x32_bf16(af[m], bfr[n], acc[m][n], 0, 0, 0);
  }
}

// ---------------------------------------------------------------------------
// QKV GEMM: 128x64 tiles, grid (36,25)=900 blocks. Scatter bf16 q/k/v.
// 64-wide n-tile lies in exactly one (which, head) block.
// ---------------------------------------------------------------------------
__global__ __launch_bounds__(256) void qkv_gemm_mfma(
    const unsigned short* __restrict__ Xbf, const unsigned short* __restrict__ Wbf,
    unsigned short* __restrict__ q_raw, unsigned short* __restrict__ k_raw,
    unsigned short* __restrict__ v_raw) {
  f32x4 acc[4][2] = {};
  const int m0 = blockIdx.y * 128;
  const int n0 = blockIdx.x * 64;
  gemm_core_t<128, 64>(Xbf, Wbf, C_, m0, n0, acc);
  const int lane = threadIdx.x & 63;
  const int wv = threadIdx.x >> 6;
  const int wm = wv >> 1, wn = wv & 1;
  const int fr = lane & 15, fj = (lane >> 4) * 4;
  const int which = (n0 >= 2 * C_) ? 2 : ((n0 >= C_) ? 1 : 0);
  const int h = (n0 - which * C_) >> 6;
  unsigned short* dst = (which == 0) ? q_raw : ((which == 1) ? k_raw : v_raw);
  #pragma unroll
  for (int n = 0; n < 2; ++n) {
    const int d = wn * 32 + n * 16 + fr;
    #pragma unroll
    for (int m = 0; m < 4; ++m) {
      #pragma unroll
      for (int j = 0; j < 4; ++j) {
        const int gm = m0 + wm * 64 + m * 16 + fj + j;
        if (gm < B_ * L_) {
          const int b = (gm >= L_) ? 1 : 0;
          const int l = gm - b * L_;
          dst[(((size_t)b * NH_ + h) * L_ + l) * HD_ + d] = f2bf(acc[m][n][j]);
        }
      }
    }
  }
}

// ---------------------------------------------------------------------------
// Proj GEMM: 64x64 tiles, grid (12,50)=600 blocks. + bias -> d_out f32
// ---------------------------------------------------------------------------
__global__ __launch_bounds__(256) void proj_gemm_mfma(
    const unsigned short* __restrict__ Abf, const unsigned short* __restrict__ Wobf,
    const float* __restrict__ bo, float* __restrict__ out) {
  f32x4 acc[2][2] = {};
  const int m0 = blockIdx.y * 64;
  const int n0 = blockIdx.x * 64;
  gemm_core_t<64, 64>(Abf, Wobf, C_, m0, n0, acc);
  const int lane = threadIdx.x & 63;
  const int wv = threadIdx.x >> 6;
  const int wm = wv >> 1, wn = wv & 1;
  const int fr = lane & 15, fj = (lane >> 4) * 4;
  #pragma unroll
  for (int n = 0; n < 2; ++n) {
    const int gn = n0 + wn * 32 + n * 16 + fr;
    const float bias = bo[gn];
    #pragma unroll
    for (int m = 0; m < 2; ++m) {
      #pragma unroll
      for (int j = 0; j < 4; ++j) {
        const int gm = m0 + wm * 32 + m * 16 + fj + j;
        if (gm < B_ * L_) out[(size_t)gm * C_ + gn] = acc[m][n][j] + bias;
      }
    }
  }
}

// ---------------------------------------------------------------------------
// Fused depthwise 3x3 conv + LayerNorm(64), FOUR rows per wave; bf16 inputs.
// ---------------------------------------------------------------------------
__global__ __launch_bounds__(256) void pool_ln_fused(
    const unsigned short* __restrict__ q_raw, const unsigned short* __restrict__ k_raw,
    const unsigned short* __restrict__ v_raw,
    const float* __restrict__ qw, const float* __restrict__ kw,
    const float* __restrict__ vw,
    const float* __restrict__ qg, const float* __restrict__ qb2,
    const float* __restrict__ kg, const float* __restrict__ kb2,
    const float* __restrict__ vg, const float* __restrict__ vb2,
    unsigned short* __restrict__ Qmain, unsigned short* __restrict__ Kpack,
    unsigned short* __restrict__ Vpack) {
  const int which = blockIdx.y;
  const unsigned short* in = (which == 0) ? q_raw : (which == 1) ? k_raw : v_raw;
  const float* w  = (which == 0) ? qw : (which == 1) ? kw : vw;
  const float* g  = (which == 0) ? qg : (which == 1) ? kg : vg;
  const float* bb = (which == 0) ? qb2 : (which == 1) ? kb2 : vb2;
  const float scale = (which == 1) ? SCALE_K : 1.f;

  const int quad = blockIdx.x * 4 + (threadIdx.x >> 6);  // 0..9407
  const int d = threadIdx.x & 63;
  const int row0 = quad * 4;
  const int bh = row0 / L_;
  const int l0  = row0 % L_;           // multiple of 4
  const int t  = l0 / S_;
  const int sq = l0 % S_;
  const int x = sq / W_, y = sq % W_;  // y multiple of 4
  const unsigned short* base = in + ((size_t)bh * L_ + t * S_) * HD_ + d;

  float acc0 = 0.f, acc1 = 0.f, acc2 = 0.f, acc3 = 0.f;
  #pragma unroll
  for (int dx = 0; dx < 3; ++dx) {
    const int xx = x + dx - 1;
    if (xx < 0 || xx >= H_) continue;
    const unsigned short* rb = base + (size_t)xx * W_ * HD_;
    const float w0 = w[(dx*3 + 0) * HD_ + d];
    const float w1 = w[(dx*3 + 1) * HD_ + d];
    const float w2 = w[(dx*3 + 2) * HD_ + d];
    const float cm1 = (y > 0)     ? bf2f(rb[(y-1) * HD_]) : 0.f;
    const float c0  = bf2f(rb[(y+0) * HD_]);
    const float c1  = bf2f(rb[(y+1) * HD_]);
    const float c2  = bf2f(rb[(y+2) * HD_]);
    const float c3  = bf2f(rb[(y+3) * HD_]);
    const float c4  = (y+4 < W_)  ? bf2f(rb[(y+4) * HD_]) : 0.f;
    acc0 += cm1*w0 + c0*w1 + c1*w2;
    acc1 += c0*w0  + c1*w1 + c2*w2;
    acc2 += c1*w0  + c2*w1 + c3*w2;
    acc3 += c2*w0  + c3*w1 + c4*w2;
  }
  float s0a = acc0, s0b = acc0*acc0, s1a = acc1, s1b = acc1*acc1;
  float s2a = acc2, s2b = acc2*acc2, s3a = acc3, s3b = acc3*acc3;
  #pragma unroll
  for (int off = 32; off; off >>= 1) {
    s0a += __shfl_xor(s0a, off); s0b += __shfl_xor(s0b, off);
    s1a += __shfl_xor(s1a, off); s1b += __shfl_xor(s1b, off);
    s2a += __shfl_xor(s2a, off); s2b += __shfl_xor(s2b, off);
    s3a += __shfl_xor(s3a, off); s3b += __shfl_xor(s3b, off);
  }
  const float gd = g[d], bd = bb[d];
  const float mu0 = s0a * (1.f/64.f), var0 = s0b * (1.f/64.f) - mu0*mu0;
  const float mu1 = s1a * (1.f/64.f), var1 = s1b * (1.f/64.f) - mu1*mu1;
  const float mu2 = s2a * (1.f/64.f), var2 = s2b * (1.f/64.f) - mu2*mu2;
  const float mu3 = s3a * (1.f/64.f), var3 = s3b * (1.f/64.f) - mu3*mu3;
  const float f0 = ((acc0 - mu0) * rsqrtf(var0 + LN_EPS) * gd + bd) * scale;
  const float f1 = ((acc1 - mu1) * rsqrtf(var1 + LN_EPS) * gd + bd) * scale;
  const float f2 = ((acc2 - mu2) * rsqrtf(var2 + LN_EPS) * gd + bd) * scale;
  const float f3 = ((acc3 - mu3) * rsqrtf(var3 + LN_EPS) * gd + bd) * scale;

  if (which == 1) {
    const unsigned short v0 = f2bf(f0), v1 = f2bf(f1);
    const unsigned short v2 = f2bf(f2), v3 = f2bf(f3);
    const int kt = l0 >> 5;
    const int c = d >> 4;
    const int lane2 = (((d >> 3) & 1) << 5) | (l0 & 31);
    unsigned short* kp = Kpack + ((((size_t)bh * 49 + kt) * 4 + c) * 64 + lane2) * 8 + (d & 7);
    kp[0] = v0; kp[8] = v1; kp[16] = v2; kp[24] = v3;
  } else if (which == 0) {
    Qmain[(size_t)(row0 + 0) * 64 + d] = f2bf(f0);
    Qmain[(size_t)(row0 + 1) * 64 + d] = f2bf(f1);
    Qmain[(size_t)(row0 + 2) * 64 + d] = f2bf(f2);
    Qmain[(size_t)(row0 + 3) * 64 + d] = f2bf(f3);
  } else {
    const int kt = l0 >> 5;
    const int c = ((d >> 5) << 1) | ((l0 >> 4) & 1);
    const int lane2 = (((l0 >> 3) & 1) << 5) | (d & 31);
    const int e = l0 & 7;   // 0 or 4
    u32x2 ov;
    ov.x = cvtpk(f0, f1);
    ov.y = cvtpk(f2, f3);
    *(u32x2*)(Vpack + ((((size_t)bh * 49 + kt) * 4 + c) * 64 + lane2) * 8 + e) = ov;
  }
}

// ---------------------------------------------------------------------------
// rel-pos via MFMA: P_h = Q*Rhb^T, P_w = Q*Rwb^T; bias rows are contiguous
// reversed slices of P. Writes QbiasPack fragment-order (incl. zero T-block).
// ---------------------------------------------------------------------------
__global__ __launch_bounds__(64) void relpos_mfma(
    const unsigned short* __restrict__ Qmain,
    const unsigned short* __restrict__ Rhb,
    const unsigned short* __restrict__ Rwb,
    unsigned short* __restrict__ QbiasPack) {
  __shared__ float P[16][128];
  const int qt16 = blockIdx.x;        // 0..48
  const int bt = blockIdx.y;          // 0..47
  const int bh = bt >> 1, t = bt & 1;
  const int lane = threadIdx.x;
  const int fr = lane & 15, fk = (lane >> 4) * 8;

  const size_t rowbase = (size_t)bh * L_ + t * S_ + qt16 * 16;
  const unsigned short* arow = Qmain + (rowbase + fr) * 64 + fk;
  const bf16x8 a0 = *(const bf16x8*)(arow);
  const bf16x8 a1 = *(const bf16x8*)(arow + 32);

  f32x4 acch[4] = {}, accw[4] = {};
  #pragma unroll
  for (int n = 0; n < 4; ++n) {
    const unsigned short* bh_ = Rhb + (n * 16 + fr) * 64 + fk;
    const unsigned short* bw_ = Rwb + (n * 16 + fr) * 64 + fk;
    acch[n] = __builtin_amdgcn_mfma_f32_16x16x32_bf16(a0, *(const bf16x8*)bh_, acch[n], 0, 0, 0);
    acch[n] = __builtin_amdgcn_mfma_f32_16x16x32_bf16(a1, *(const bf16x8*)(bh_ + 32), acch[n], 0, 0, 0);
    accw[n] = __builtin_amdgcn_mfma_f32_16x16x32_bf16(a0, *(const bf16x8*)bw_, accw[n], 0, 0, 0);
    accw[n] = __builtin_amdgcn_mfma_f32_16x16x32_bf16(a1, *(const bf16x8*)(bw_ + 32), accw[n], 0, 0, 0);
  }
  #pragma unroll
  for (int n = 0; n < 4; ++n)
    #pragma unroll
    for (int j = 0; j < 4; ++j) {
      P[(lane >> 4) * 4 + j][n * 16 + fr]      = acch[n][j];
      P[(lane >> 4) * 4 + j][64 + n * 16 + fr] = accw[n][j];
    }
  __syncthreads();

  if (lane < 56) {
    const int e0 = lane * 2;          // bias element pair
    const int tb = e0 / 56;
    const int tw0 = e0 % 56;
    const int cb = e0 >> 4;
    const int hi2 = (e0 >> 3) & 1;
    const int ee = e0 & 7;
    #pragma unroll
    for (int r = 0; r < 16; ++r) {
      const int gl = t * S_ + qt16 * 16 + r;
      const int sq = qt16 * 16 + r;
      const int x = sq / W_, y = sq % W_;
      float v0 = 0.f, v1 = 0.f;
      if (tb == t) {
        if (tw0 < 28) {
          v0 = P[r][x - tw0 + 27];
          v1 = P[r][x - tw0 + 26];
        } else {
          const int k0 = tw0 - 28;
          v0 = P[r][64 + y - k0 + 27];
          v1 = P[r][64 + y - k0 + 26];
        }
      }
      const int lane2 = (hi2 << 5) | (gl & 31);
      unsigned short* dst = QbiasPack +
          ((((size_t)bh * 49 + (gl >> 5)) * 7 + cb) * 64 + lane2) * 8 + ee;
      *(uint_*)dst = cvtpk(v0, v1);
    }
  }
}

// ---------------------------------------------------------------------------
// MFMA flash attention. 256 thr (4 waves), grid 1176 (XCD-swizzled).
// qbias staged in LDS (block-constant); fragment-packed K/V; fixed-base SM.
// ---------------------------------------------------------------------------
__device__ __forceinline__ void load_k(
    const unsigned short* kbase, int kt,
    u32x4& k0, u32x4& k1, u32x4& k2, u32x4& k3) {
  const unsigned short* kp = kbase + (size_t)kt * 2048;
  k0 = *(const u32x4*)(kp);
  k1 = *(const u32x4*)(kp + 512);
  k2 = *(const u32x4*)(kp + 1024);
  k3 = *(const u32x4*)(kp + 1536);
}

__device__ __forceinline__ void load_v(
    const unsigned short* vbase, int kt,
    u32x4& va, u32x4& vb, u32x4& vc, u32x4& vd) {
  const unsigned short* vp = vbase + (size_t)kt * 2048;
  va = *(const u32x4*)(vp);
  vb = *(const u32x4*)(vp + 512);
  vc = *(const u32x4*)(vp + 1024);
  vd = *(const u32x4*)(vp + 1536);
}

template<bool BIAS>
__device__ __forceinline__ f32x16 qk_tile(
    int kt, int lo, int hi, const u32x4 (&qf)[4],
    const unsigned short* qbias_lds,
    u32x4 k0, u32x4 k1, u32x4 k2, u32x4 k3) {
  f32x16 s = {};
  s = __builtin_amdgcn_mfma_f32_32x32x16_bf16(BC8(k0), BC8(qf[0]), s, 0, 0, 0);
  s = __builtin_amdgcn_mfma_f32_32x32x16_bf16(BC8(k1), BC8(qf[1]), s, 0, 0, 0);
  s = __builtin_amdgcn_mfma_f32_32x32x16_bf16(BC8(k2), BC8(qf[2]), s, 0, 0, 0);
  s = __builtin_amdgcn_mfma_f32_32x32x16_bf16(BC8(k3), BC8(qf[3]), s, 0, 0, 0);
  if (BIAS) {
    const int kr = kt * 32 + lo;
    const int t = (kr >= S_) ? 1 : 0;
    const int sk = kr - t * S_;
    const int x = sk / W_, y = sk - x * W_;
    const int p1 = t*56 + x;
    const int p2 = t*56 + 28 + y;
    const uint_ v1 = 0x3F80u << ((p1 & 1) << 4);
    const uint_ v2 = 0x3F80u << ((p2 & 1) << 4);
    const int g1 = p1 >> 3, g2 = p2 >> 3;
    const int w1 = (p1 >> 1) & 3, w2 = (p2 >> 1) & 3;
    #pragma unroll
    for (int c = 0; c < 7; ++c) {
      const int gg = 2*c + hi;
      u32x4 oh;
      oh.x = ((g1 == gg && w1 == 0) ? v1 : 0u) | ((g2 == gg && w2 == 0) ? v2 : 0u);
      oh.y = ((g1 == gg && w1 == 1) ? v1 : 0u) | ((g2 == gg && w2 == 1) ? v2 : 0u);
      oh.z = ((g1 == gg && w1 == 2) ? v1 : 0u) | ((g2 == gg && w2 == 2) ? v2 : 0u);
      oh.w = ((g1 == gg && w1 == 3) ? v1 : 0u) | ((g2 == gg && w2 == 3) ? v2 : 0u);
      const u32x4 qb = *(const u32x4*)(qbias_lds + c * 512);
      s = __builtin_amdgcn_mfma_f32_32x32x16_bf16(BC8(oh), BC8(qb), s, 0, 0, 0);
    }
  }
  return s;
}

__device__ __forceinline__ void sm_pv(
    const f32x16& s,
    u32x4 va, u32x4 vb, u32x4 vc, u32x4 vd,
    f32x16& acc0, f32x16& acc1, float& l_run) {
  uint_ pw0, pw1, pw2, pw3, pw4, pw5, pw6, pw7;
  {
    float a, b;
    a = exp2f(s[0]);  b = exp2f(s[1]);  l_run += a+b; pw0 = cvtpk(a,b);
    a = exp2f(s[2]);  b = exp2f(s[3]);  l_run += a+b; pw1 = cvtpk(a,b);
    a = exp2f(s[4]);  b = exp2f(s[5]);  l_run += a+b; pw2 = cvtpk(a,b);
    a = exp2f(s[6]);  b = exp2f(s[7]);  l_run += a+b; pw3 = cvtpk(a,b);
    a = exp2f(s[8]);  b = exp2f(s[9]);  l_run += a+b; pw4 = cvtpk(a,b);
    a = exp2f(s[10]); b = exp2f(s[11]); l_run += a+b; pw5 = cvtpk(a,b);
    a = exp2f(s[12]); b = exp2f(s[13]); l_run += a+b; pw6 = cvtpk(a,b);
    a = exp2f(s[14]); b = exp2f(s[15]); l_run += a+b; pw7 = cvtpk(a,b);
  }
  auto sA = __builtin_amdgcn_permlane32_swap(pw0, pw2, false, false);
  auto sB = __builtin_amdgcn_permlane32_swap(pw1, pw3, false, false);
  auto sC = __builtin_amdgcn_permlane32_swap(pw4, pw6, false, false);
  auto sD = __builtin_amdgcn_permlane32_swap(pw5, pw7, false, false);
  u32x4 pa0, pa1;
  pa0.x = sA[0]; pa0.y = sB[0]; pa0.z = sA[1]; pa0.w = sB[1];
  pa1.x = sC[0]; pa1.y = sD[0]; pa1.z = sC[1]; pa1.w = sD[1];

  acc0 = __builtin_amdgcn_mfma_f32_32x32x16_bf16(BC8(pa0), BC8(va), acc0, 0, 0, 0);
  acc0 = __builtin_amdgcn_mfma_f32_32x32x16_bf16(BC8(pa1), BC8(vb), acc0, 0, 0, 0);
  acc1 = __builtin_amdgcn_mfma_f32_32x32x16_bf16(BC8(pa0), BC8(vc), acc1, 0, 0, 0);
  acc1 = __builtin_amdgcn_mfma_f32_32x32x16_bf16(BC8(pa1), BC8(vd), acc1, 0, 0, 0);
}

__device__ __forceinline__ bool bias_needed(int kt, int qt) {
  const int kmin = (kt * 32 >= S_) ? 1 : 0;
  const int kmax = (kt * 32 + 31 >= S_) ? 1 : 0;
  const int qmin = (qt * 32 >= S_) ? 1 : 0;
  const int qmax = (qt * 32 + 31 >= S_) ? 1 : 0;
  return (kmin <= qmax) && (qmin <= kmax);
}

__global__ __launch_bounds__(256) void attn_mfma(
    const unsigned short* __restrict__ Qmain, const unsigned short* __restrict__ QbiasPack,
    const unsigned short* __restrict__ Kpack, const unsigned short* __restrict__ Vpack,
    unsigned short* __restrict__ Abf) {
  __shared__ float red_acc[3][32][64];
  __shared__ float red_l[4][32];
  __shared__ __align__(16) unsigned short qb_lds[3584];

  const int id0 = blockIdx.x;                  // 1176 = 8 * 147
  const int swz = (id0 & 7) * 147 + (id0 >> 3);
  const int qt = swz % 49;
  const int bh = swz / 49;

  const int lane = threadIdx.x & 63;
  const int wv = threadIdx.x >> 6;             // 0..3
  const int lo = lane & 31, hi = lane >> 5;
  const int q0 = qt * 32;

  {
    const unsigned short* src = QbiasPack + ((size_t)bh * 49 + qt) * 3584;
    for (int i = wv; i < 7; i += 4)
      gload16(src + i * 512 + lane * 8, qb_lds + i * 512);
  }

  const unsigned short* qrow = Qmain + ((size_t)bh * L_ + q0 + lo) * 64 + hi * 8;
  u32x4 qf[4];
  #pragma unroll
  for (int c = 0; c < 4; ++c) qf[c] = *(const u32x4*)(qrow + c * 16);
  const unsigned short* qbias_lds = qb_lds + lane * 8;

  const unsigned short* kbase = Kpack + (size_t)bh * 49 * 2048 + lane * 8;
  const unsigned short* vbase = Vpack + (size_t)bh * 49 * 2048 + lane * 8;

  f32x16 acc0 = {}, acc1 = {};
  float l_run = 0.f;
  const int nt = (49 - wv + 3) >> 2;           // wave wv: tiles kt = wv + 4*j

  __syncthreads();   // qb_lds ready

  #define KT(j) (wv + 4 * (j))
  #define QK(j, K0, K1, K2, K3) \
    (bias_needed(KT(j), qt) \
      ? qk_tile<true>(KT(j), lo, hi, qf, qbias_lds, K0, K1, K2, K3) \
      : qk_tile<false>(KT(j), lo, hi, qf, qbias_lds, K0, K1, K2, K3))

  u32x4 kA0, kA1, kA2, kA3, kB0, kB1, kB2, kB3;
  u32x4 va, vb, vc, vd;

  load_k(kbase, KT(0), kA0, kA1, kA2, kA3);
  load_k(kbase, KT(1), kB0, kB1, kB2, kB3);
  f32x16 s_prev = QK(0, kA0, kA1, kA2, kA3);

  int j = 1;
  for (; j + 1 < nt; j += 2) {
    load_v(vbase, KT(j - 1), va, vb, vc, vd);
    f32x16 s_cur = QK(j, kB0, kB1, kB2, kB3);
    load_k(kbase, KT(j + 1), kA0, kA1, kA2, kA3);
    sm_pv(s_prev, va, vb, vc, vd, acc0, acc1, l_run);
    s_prev = s_cur;
    load_v(vbase, KT(j), va, vb, vc, vd);
    f32x16 s_cur2 = QK(j + 1, kA0, kA1, kA2, kA3);
    const int pf = (j + 2 < nt) ? j + 2 : nt - 1;
    load_k(kbase, KT(pf), kB0, kB1, kB2, kB3);
    sm_pv(s_prev, va, vb, vc, vd, acc0, acc1, l_run);
    s_prev = s_cur2;
  }
  if (j < nt) {
    load_v(vbase, KT(j - 1), va, vb, vc, vd);
    f32x16 s_cur = QK(j, kB0, kB1, kB2, kB3);
    sm_pv(s_prev, va, vb, vc, vd, acc0, acc1, l_run);
    s_prev = s_cur;
  }
  load_v(vbase, KT(nt - 1), va, vb, vc, vd);
  sm_pv(s_prev, va, vb, vc, vd, acc0, acc1, l_run);
  #undef QK
  #undef KT

  l_run += __shfl_xor(l_run, 32);

  if (hi == 0) red_l[wv][lo] = l_run;
  if (wv >= 1) {
    #pragma unroll
    for (int r = 0; r < 16; ++r) {
      const int row = (r & 3) + 8*(r >> 2) + 4*hi;
      red_acc[wv-1][row][lo]      = acc0[r];
      red_acc[wv-1][row][32 + lo] = acc1[r];
    }
  }
  __syncthreads();
  if (wv == 0) {
    const int b = bh / NH_, h = bh % NH_;
    #pragma unroll
    for (int r = 0; r < 16; ++r) {
      const int row = (r & 3) + 8*(r >> 2) + 4*hi;
      const float inv = 1.0f / (red_l[0][row] + red_l[1][row] +
                                red_l[2][row] + red_l[3][row]);
      const float o0 = (acc0[r] + red_acc[0][row][lo] +
                        red_acc[1][row][lo] + red_acc[2][row][lo]) * inv;
      const float o1 = (acc1[r] + red_acc[0][row][32+lo] +
                        red_acc[1][row][32+lo] + red_acc[2][row][32+lo]) * inv;
      const size_t qoff = ((size_t)bh * L_ + q0 + row) * 64 + lo;
      const size_t ooff = ((size_t)(b * L_ + q0 + row)) * C_ + h * 64 + lo;
      Abf[ooff]      = f2bf(o0 + bf2f(Qmain[qoff]));
      Abf[ooff + 32] = f2bf(o1 + bf2f(Qmain[qoff + 32]));
    }
  }
}

// ---------------------------------------------------------------------------
extern "C" void kernel_launch(void* const* d_in, const int* in_sizes, int n_in,
                              void* d_out, int out_size, void* d_ws, size_t ws_size,
                              hipStream_t stream) {
  const float* x         = (const float*)d_in[0];
  const float* qkv_w     = (const float*)d_in[1];
  const float* out_w     = (const float*)d_in[2];
  const float* out_b     = (const float*)d_in[3];
  const float* q_pool_w  = (const float*)d_in[4];
  const float* k_pool_w  = (const float*)d_in[5];
  const float* v_pool_w  = (const float*)d_in[6];
  const float* q_ln_g    = (const float*)d_in[7];
  const float* q_ln_b    = (const float*)d_in[8];
  const float* k_ln_g    = (const float*)d_in[9];
  const float* k_ln_b    = (const float*)d_in[10];
  const float* v_ln_g    = (const float*)d_in[11];
  const float* v_ln_b    = (const float*)d_in[12];
  const float* rel_pos_h = (const float*)d_in[13];
  const float* rel_pos_w = (const float*)d_in[14];

  float* R = (float*)d_ws;
  const size_t NQ = (size_t)B_ * NH_ * L_ * HD_;   // 2,408,448 f32 slots
  unsigned short* q_raw = (unsigned short*)R;      // bf16
  unsigned short* Abf = (unsigned short*)R;        // alias (q_raw dead after pool)
  unsigned short* k_raw = (unsigned short*)(R + NQ);
  unsigned short* v_raw = (unsigned short*)(R + 2*NQ);
  const size_t D_off = 3*NQ;
  unsigned short* Xbf   = (unsigned short*)(R + D_off);
  unsigned short* Qmain = (unsigned short*)(R + D_off);
  const size_t E_off = D_off + 1228800;
  unsigned short* Kpack = (unsigned short*)(R + E_off);
  const size_t F_off = E_off + 1204224;
  unsigned short* Wbf   = (unsigned short*)(R + F_off);
  unsigned short* Vpack = (unsigned short*)(R + F_off);
  const size_t G_off = F_off + 1204224;
  unsigned short* Wobf = (unsigned short*)(R + G_off);
  const size_t H_off = G_off + 294912;
  unsigned short* QbiasPack = (unsigned short*)(R + H_off);
  const size_t I_off = H_off + 2107392;
  unsigned short* Rhb = (unsigned short*)(R + I_off);
  unsigned short* Rwb = (unsigned short*)(R + I_off + 2048);

  cvt_all<<<2328, 256, 0, stream>>>(x, 3136*768, Xbf,
                                    qkv_w, 2304*768, Wbf,
                                    out_w, 768*768, Wobf);
  cvt_rel<<<16, 256, 0, stream>>>(rel_pos_h, rel_pos_w, Rhb, Rwb);
  qkv_gemm_mfma<<<dim3(36, 25), 256, 0, stream>>>(Xbf, Wbf, q_raw, k_raw, v_raw);
  pool_ln_fused<<<dim3(2352, 3), 256, 0, stream>>>(
      q_raw, k_raw, v_raw, q_pool_w, k_pool_w, v_pool_w,
      q_ln_g, q_ln_b, k_ln_g, k_ln_b, v_ln_g, v_ln_b, Qmain, Kpack, Vpack);
  relpos_mfma<<<dim3(49, 48), 64, 0, stream>>>(Qmain, Rhb, Rwb, QbiasPack);
  attn_mfma<<<1176, 256, 0, stream>>>(Qmain, QbiasPack, Kpack, Vpack, Abf);
  proj_gemm_mfma<<<dim3(12, 50), 256, 0, stream>>>(Abf, Wobf, out_b, (float*)d_out);
}

// Round 21
// 123.413 us; speedup vs baseline: 1.0092x; 1.0092x over previous
//
#include <hip/hip_runtime.h>
#include <math.h>

#define B_ 2
#define T_ 2
#define H_ 28
#define W_ 28
#define S_ (H_*W_)      /* 784  */
#define L_ (T_*S_)      /* 1568 */
#define C_ 768
#define NH_ 12
#define HD_ 64
#define LN_EPS 1e-5f
#define LOG2E 1.4426950408889634f
#define SCALE_K (0.125f * LOG2E)   /* hd^-0.5 * log2e folded into K' */

typedef unsigned int uint_;
typedef unsigned int u32x2 __attribute__((ext_vector_type(2)));
typedef unsigned int u32x4 __attribute__((ext_vector_type(4)));
typedef __bf16 bf16x8 __attribute__((ext_vector_type(8)));
typedef float f32x4 __attribute__((ext_vector_type(4)));
typedef float f32x16 __attribute__((ext_vector_type(16)));

#define BC8(x) __builtin_bit_cast(bf16x8, (x))

__device__ __forceinline__ unsigned short f2bf(float f) {
  uint_ u = __builtin_bit_cast(uint_, f);
  u += 0x7FFFu + ((u >> 16) & 1u);
  return (unsigned short)(u >> 16);
}
__device__ __forceinline__ float bf2f(unsigned short h) {
  return __builtin_bit_cast(float, ((uint_)h) << 16);
}
__device__ __forceinline__ uint_ cvtpk(float a, float b) {
  uint_ r;
  asm("v_cvt_pk_bf16_f32 %0, %1, %2" : "=v"(r) : "v"(a), "v"(b));
  return r;
}
__device__ __forceinline__ void gload16(const void* g, void* l) {
  __builtin_amdgcn_global_load_lds(
      (const __attribute__((address_space(1))) unsigned int*)g,
      (__attribute__((address_space(3))) unsigned int*)l, 16, 0, 0);
}

// ---------------------------------------------------------------------------
// Fused f32 -> bf16 convert: x / qkv_w / out_w, plus rel tables (LOG2E-scaled,
// zero-padded to [64][64]) as a 4th range. Blocks 0..2327 cover exactly
// (3136+2304+768)*768 = 4,767,744 elements; blocks 2328..2331 cover 8192 rel.
// ---------------------------------------------------------------------------
__global__ __launch_bounds__(256) void cvt_all(
    const float* __restrict__ s0, int n0, unsigned short* __restrict__ d0,
    const float* __restrict__ s1, int n1, unsigned short* __restrict__ d1,
    const float* __restrict__ s2, int n2, unsigned short* __restrict__ d2,
    const float* __restrict__ rph, const float* __restrict__ rpw,
    unsigned short* __restrict__ Rhb, unsigned short* __restrict__ Rwb) {
  int i = (blockIdx.x * 256 + threadIdx.x) * 8;
  const int ntot = n0 + n1 + n2;
  if (i >= ntot) {                     // rel-table segment: 8192 u16 outputs
    i -= ntot;
    if (i >= 8192) return;
    #pragma unroll
    for (int e = 0; e < 8; ++e) {
      const int o = i + e;
      const int idx = o & 4095;
      const int j = idx >> 6;
      const float* src = (o < 4096) ? rph : rpw;
      unsigned short* dst = (o < 4096) ? Rhb : Rwb;
      dst[idx] = (j < 2*H_-1) ? f2bf(src[idx] * LOG2E) : 0;
    }
    return;
  }
  const float* s; unsigned short* d;
  if (i < n0) { s = s0; d = d0; }
  else if (i < n0 + n1) { i -= n0; s = s1; d = d1; }
  else { i -= n0 + n1; s = s2; d = d2; }
  float4 a = *(const float4*)(s + i);
  float4 b = *(const float4*)(s + i + 4);
  u32x4 o;
  o.x = cvtpk(a.x, a.y); o.y = cvtpk(a.z, a.w);
  o.z = cvtpk(b.x, b.y); o.w = cvtpk(b.z, b.w);
  *(u32x4*)(d + i) = o;
}

// ---------------------------------------------------------------------------
// Templated bf16 MFMA GEMM core: C = A * B^T, BMxBN tile, BK=32, 4 waves
// (2x2), wave covers (BM/2)x(BN/2). Single-buffered LDS, 2 barriers/K-step.
// ---------------------------------------------------------------------------
template<int BM, int BN>
__device__ __forceinline__ void gemm_core_t(
    const unsigned short* __restrict__ A, const unsigned short* __restrict__ Bm,
    int K, int m0, int n0, f32x4 (&acc)[BM/32][BN/32]) {
  constexpr int MF = BM / 32;
  constexpr int NF = BN / 32;
  __shared__ __align__(16) unsigned short As[BM * 32];
  __shared__ __align__(16) unsigned short Bs[BN * 32];
  const int tid = threadIdx.x;
  const int lane = tid & 63;
  const int wv = tid >> 6;
  const int wm = wv >> 1, wn = wv & 1;
  const int srow = tid >> 2, scol = (tid & 3) * 8;
  const int fr = lane & 15, fk = (lane >> 4) * 8;
  const unsigned short* ag = A + (size_t)(m0 + srow) * K + scol;
  const unsigned short* bg = Bm + (size_t)(n0 + srow) * K + scol;
  unsigned short* asd = As + tid * 8;
  unsigned short* bsd = Bs + tid * 8;
  const int arow = wm * (BM / 2) + fr;
  const int brow = wn * (BN / 2) + fr;
  for (int k0 = 0; k0 < K; k0 += 32) {
    __syncthreads();
    #pragma unroll
    for (int r = 0; r < BM / 64; ++r)
      gload16(ag + (size_t)(r * 64) * K + k0, asd + r * 2048);
    #pragma unroll
    for (int r = 0; r < BN / 64; ++r)
      gload16(bg + (size_t)(r * 64) * K + k0, bsd + r * 2048);
    __syncthreads();
    bf16x8 af[MF], bfr[NF];
    #pragma unroll
    for (int m = 0; m < MF; ++m)
      af[m] = *(const bf16x8*)(As + (arow + m * 16) * 32 + fk);
    #pragma unroll
    for (int n = 0; n < NF; ++n)
      bfr[n] = *(const bf16x8*)(Bs + (brow + n * 16) * 32 + fk);
    #pragma unroll
    for (int m = 0; m < MF; ++m)
      #pragma unroll
      for (int n = 0; n < NF; ++n)
        acc[m][n] = __builtin_amdgcn_mfma_f32_16x16x32_bf16(af[m], bfr[n], acc[m][n], 0, 0, 0);
  }
}

// ---------------------------------------------------------------------------
// QKV GEMM: 128x64 tiles, grid (36,25)=900 blocks. Scatter bf16 q/k/v.
// m-guard REQUIRED: pad rows (gm>=3136) would wrap into head h+1 rows of b=1.
// ---------------------------------------------------------------------------
__global__ __launch_bounds__(256) void qkv_gemm_mfma(
    const unsigned short* __restrict__ Xbf, const unsigned short* __restrict__ Wbf,
    unsigned short* __restrict__ q_raw, unsigned short* __restrict__ k_raw,
    unsigned short* __restrict__ v_raw) {
  f32x4 acc[4][2] = {};
  const int m0 = blockIdx.y * 128;
  const int n0 = blockIdx.x * 64;
  gemm_core_t<128, 64>(Xbf, Wbf, C_, m0, n0, acc);
  const int lane = threadIdx.x & 63;
  const int wv = threadIdx.x >> 6;
  const int wm = wv >> 1, wn = wv & 1;
  const int fr = lane & 15, fj = (lane >> 4) * 4;
  const int which = (n0 >= 2 * C_) ? 2 : ((n0 >= C_) ? 1 : 0);
  const int h = (n0 - which * C_) >> 6;
  unsigned short* dst = (which == 0) ? q_raw : ((which == 1) ? k_raw : v_raw);
  #pragma unroll
  for (int n = 0; n < 2; ++n) {
    const int d = wn * 32 + n * 16 + fr;
    #pragma unroll
    for (int m = 0; m < 4; ++m) {
      #pragma unroll
      for (int j = 0; j < 4; ++j) {
        const int gm = m0 + wm * 64 + m * 16 + fj + j;
        if (gm < B_ * L_) {
          const int b = (gm >= L_) ? 1 : 0;
          const int l = gm - b * L_;
          dst[(((size_t)b * NH_ + h) * L_ + l) * HD_ + d] = f2bf(acc[m][n][j]);
        }
      }
    }
  }
}

// ---------------------------------------------------------------------------
// Proj GEMM: 64x64 tiles, grid (12,50)=600 blocks. + bias -> d_out f32
// ---------------------------------------------------------------------------
__global__ __launch_bounds__(256) void proj_gemm_mfma(
    const unsigned short* __restrict__ Abf, const unsigned short* __restrict__ Wobf,
    const float* __restrict__ bo, float* __restrict__ out) {
  f32x4 acc[2][2] = {};
  const int m0 = blockIdx.y * 64;
  const int n0 = blockIdx.x * 64;
  gemm_core_t<64, 64>(Abf, Wobf, C_, m0, n0, acc);
  const int lane = threadIdx.x & 63;
  const int wv = threadIdx.x >> 6;
  const int wm = wv >> 1, wn = wv & 1;
  const int fr = lane & 15, fj = (lane >> 4) * 4;
  #pragma unroll
  for (int n = 0; n < 2; ++n) {
    const int gn = n0 + wn * 32 + n * 16 + fr;
    const float bias = bo[gn];
    #pragma unroll
    for (int m = 0; m < 2; ++m) {
      #pragma unroll
      for (int j = 0; j < 4; ++j) {
        const int gm = m0 + wm * 32 + m * 16 + fj + j;
        if (gm < B_ * L_) out[(size_t)gm * C_ + gn] = acc[m][n][j] + bias;
      }
    }
  }
}

// ---------------------------------------------------------------------------
// Fused depthwise 3x3 conv + LayerNorm(64), FOUR rows per wave; bf16 inputs.
// ---------------------------------------------------------------------------
__global__ __launch_bounds__(256) void pool_ln_fused(
    const unsigned short* __restrict__ q_raw, const unsigned short* __restrict__ k_raw,
    const unsigned short* __restrict__ v_raw,
    const float* __restrict__ qw, const float* __restrict__ kw,
    const float* __restrict__ vw,
    const float* __restrict__ qg, const float* __restrict__ qb2,
    const float* __restrict__ kg, const float* __restrict__ kb2,
    const float* __restrict__ vg, const float* __restrict__ vb2,
    unsigned short* __restrict__ Qmain, unsigned short* __restrict__ Kpack,
    unsigned short* __restrict__ Vpack) {
  const int which = blockIdx.y;
  const unsigned short* in = (which == 0) ? q_raw : (which == 1) ? k_raw : v_raw;
  const float* w  = (which == 0) ? qw : (which == 1) ? kw : vw;
  const float* g  = (which == 0) ? qg : (which == 1) ? kg : vg;
  const float* bb = (which == 0) ? qb2 : (which == 1) ? kb2 : vb2;
  const float scale = (which == 1) ? SCALE_K : 1.f;

  const int quad = blockIdx.x * 4 + (threadIdx.x >> 6);  // 0..9407
  const int d = threadIdx.x & 63;
  const int row0 = quad * 4;
  const int bh = row0 / L_;
  const int l0  = row0 % L_;           // multiple of 4
  const int t  = l0 / S_;
  const int sq = l0 % S_;
  const int x = sq / W_, y = sq % W_;  // y multiple of 4
  const unsigned short* base = in + ((size_t)bh * L_ + t * S_) * HD_ + d;

  float acc0 = 0.f, acc1 = 0.f, acc2 = 0.f, acc3 = 0.f;
  #pragma unroll
  for (int dx = 0; dx < 3; ++dx) {
    const int xx = x + dx - 1;
    if (xx < 0 || xx >= H_) continue;
    const unsigned short* rb = base + (size_t)xx * W_ * HD_;
    const float w0 = w[(dx*3 + 0) * HD_ + d];
    const float w1 = w[(dx*3 + 1) * HD_ + d];
    const float w2 = w[(dx*3 + 2) * HD_ + d];
    const float cm1 = (y > 0)     ? bf2f(rb[(y-1) * HD_]) : 0.f;
    const float c0  = bf2f(rb[(y+0) * HD_]);
    const float c1  = bf2f(rb[(y+1) * HD_]);
    const float c2  = bf2f(rb[(y+2) * HD_]);
    const float c3  = bf2f(rb[(y+3) * HD_]);
    const float c4  = (y+4 < W_)  ? bf2f(rb[(y+4) * HD_]) : 0.f;
    acc0 += cm1*w0 + c0*w1 + c1*w2;
    acc1 += c0*w0  + c1*w1 + c2*w2;
    acc2 += c1*w0  + c2*w1 + c3*w2;
    acc3 += c2*w0  + c3*w1 + c4*w2;
  }
  float s0a = acc0, s0b = acc0*acc0, s1a = acc1, s1b = acc1*acc1;
  float s2a = acc2, s2b = acc2*acc2, s3a = acc3, s3b = acc3*acc3;
  #pragma unroll
  for (int off = 32; off; off >>= 1) {
    s0a += __shfl_xor(s0a, off); s0b += __shfl_xor(s0b, off);
    s1a += __shfl_xor(s1a, off); s1b += __shfl_xor(s1b, off);
    s2a += __shfl_xor(s2a, off); s2b += __shfl_xor(s2b, off);
    s3a += __shfl_xor(s3a, off); s3b += __shfl_xor(s3b, off);
  }
  const float gd = g[d], bd = bb[d];
  const float mu0 = s0a * (1.f/64.f), var0 = s0b * (1.f/64.f) - mu0*mu0;
  const float mu1 = s1a * (1.f/64.f), var1 = s1b * (1.f/64.f) - mu1*mu1;
  const float mu2 = s2a * (1.f/64.f), var2 = s2b * (1.f/64.f) - mu2*mu2;
  const float mu3 = s3a * (1.f/64.f), var3 = s3b * (1.f/64.f) - mu3*mu3;
  const float f0 = ((acc0 - mu0) * rsqrtf(var0 + LN_EPS) * gd + bd) * scale;
  const float f1 = ((acc1 - mu1) * rsqrtf(var1 + LN_EPS) * gd + bd) * scale;
  const float f2 = ((acc2 - mu2) * rsqrtf(var2 + LN_EPS) * gd + bd) * scale;
  const float f3 = ((acc3 - mu3) * rsqrtf(var3 + LN_EPS) * gd + bd) * scale;

  if (which == 1) {
    const unsigned short v0 = f2bf(f0), v1 = f2bf(f1);
    const unsigned short v2 = f2bf(f2), v3 = f2bf(f3);
    const int kt = l0 >> 5;
    const int c = d >> 4;
    const int lane2 = (((d >> 3) & 1) << 5) | (l0 & 31);
    unsigned short* kp = Kpack + ((((size_t)bh * 49 + kt) * 4 + c) * 64 + lane2) * 8 + (d & 7);
    kp[0] = v0; kp[8] = v1; kp[16] = v2; kp[24] = v3;
  } else if (which == 0) {
    Qmain[(size_t)(row0 + 0) * 64 + d] = f2bf(f0);
    Qmain[(size_t)(row0 + 1) * 64 + d] = f2bf(f1);
    Qmain[(size_t)(row0 + 2) * 64 + d] = f2bf(f2);
    Qmain[(size_t)(row0 + 3) * 64 + d] = f2bf(f3);
  } else {
    const int kt = l0 >> 5;
    const int c = ((d >> 5) << 1) | ((l0 >> 4) & 1);
    const int lane2 = (((l0 >> 3) & 1) << 5) | (d & 31);
    const int e = l0 & 7;   // 0 or 4
    u32x2 ov;
    ov.x = cvtpk(f0, f1);
    ov.y = cvtpk(f2, f3);
    *(u32x2*)(Vpack + ((((size_t)bh * 49 + kt) * 4 + c) * 64 + lane2) * 8 + e) = ov;
  }
}

// ---------------------------------------------------------------------------
// rel-pos via MFMA: P_h = Q*Rhb^T, P_w = Q*Rwb^T; bias rows are contiguous
// reversed slices of P. Writes QbiasPack fragment-order (incl. zero T-block).
// ---------------------------------------------------------------------------
__global__ __launch_bounds__(64) void relpos_mfma(
    const unsigned short* __restrict__ Qmain,
    const unsigned short* __restrict__ Rhb,
    const unsigned short* __restrict__ Rwb,
    unsigned short* __restrict__ QbiasPack) {
  __shared__ float P[16][128];
  const int qt16 = blockIdx.x;        // 0..48
  const int bt = blockIdx.y;          // 0..47
  const int bh = bt >> 1, t = bt & 1;
  const int lane = threadIdx.x;
  const int fr = lane & 15, fk = (lane >> 4) * 8;

  const size_t rowbase = (size_t)bh * L_ + t * S_ + qt16 * 16;
  const unsigned short* arow = Qmain + (rowbase + fr) * 64 + fk;
  const bf16x8 a0 = *(const bf16x8*)(arow);
  const bf16x8 a1 = *(const bf16x8*)(arow + 32);

  f32x4 acch[4] = {}, accw[4] = {};
  #pragma unroll
  for (int n = 0; n < 4; ++n) {
    const unsigned short* bh_ = Rhb + (n * 16 + fr) * 64 + fk;
    const unsigned short* bw_ = Rwb + (n * 16 + fr) * 64 + fk;
    acch[n] = __builtin_amdgcn_mfma_f32_16x16x32_bf16(a0, *(const bf16x8*)bh_, acch[n], 0, 0, 0);
    acch[n] = __builtin_amdgcn_mfma_f32_16x16x32_bf16(a1, *(const bf16x8*)(bh_ + 32), acch[n], 0, 0, 0);
    accw[n] = __builtin_amdgcn_mfma_f32_16x16x32_bf16(a0, *(const bf16x8*)bw_, accw[n], 0, 0, 0);
    accw[n] = __builtin_amdgcn_mfma_f32_16x16x32_bf16(a1, *(const bf16x8*)(bw_ + 32), accw[n], 0, 0, 0);
  }
  #pragma unroll
  for (int n = 0; n < 4; ++n)
    #pragma unroll
    for (int j = 0; j < 4; ++j) {
      P[(lane >> 4) * 4 + j][n * 16 + fr]      = acch[n][j];
      P[(lane >> 4) * 4 + j][64 + n * 16 + fr] = accw[n][j];
    }
  __syncthreads();

  if (lane < 56) {
    const int e0 = lane * 2;          // bias element pair
    const int tb = e0 / 56;
    const int tw0 = e0 % 56;
    const int cb = e0 >> 4;
    const int hi2 = (e0 >> 3) & 1;
    const int ee = e0 & 7;
    #pragma unroll
    for (int r = 0; r < 16; ++r) {
      const int gl = t * S_ + qt16 * 16 + r;
      const int sq = qt16 * 16 + r;
      const int x = sq / W_, y = sq % W_;
      float v0 = 0.f, v1 = 0.f;
      if (tb == t) {
        if (tw0 < 28) {
          v0 = P[r][x - tw0 + 27];
          v1 = P[r][x - tw0 + 26];
        } else {
          const int k0 = tw0 - 28;
          v0 = P[r][64 + y - k0 + 27];
          v1 = P[r][64 + y - k0 + 26];
        }
      }
      const int lane2 = (hi2 << 5) | (gl & 31);
      unsigned short* dst = QbiasPack +
          ((((size_t)bh * 49 + (gl >> 5)) * 7 + cb) * 64 + lane2) * 8 + ee;
      *(uint_*)dst = cvtpk(v0, v1);
    }
  }
}

// ---------------------------------------------------------------------------
// MFMA flash attention. 256 thr (4 waves), grid 1176 (XCD-swizzled).
// qbias staged in LDS (block-constant); fragment-packed K/V; fixed-base SM.
// ---------------------------------------------------------------------------
__device__ __forceinline__ void load_k(
    const unsigned short* kbase, int kt,
    u32x4& k0, u32x4& k1, u32x4& k2, u32x4& k3) {
  const unsigned short* kp = kbase + (size_t)kt * 2048;
  k0 = *(const u32x4*)(kp);
  k1 = *(const u32x4*)(kp + 512);
  k2 = *(const u32x4*)(kp + 1024);
  k3 = *(const u32x4*)(kp + 1536);
}

__device__ __forceinline__ void load_v(
    const unsigned short* vbase, int kt,
    u32x4& va, u32x4& vb, u32x4& vc, u32x4& vd) {
  const unsigned short* vp = vbase + (size_t)kt * 2048;
  va = *(const u32x4*)(vp);
  vb = *(const u32x4*)(vp + 512);
  vc = *(const u32x4*)(vp + 1024);
  vd = *(const u32x4*)(vp + 1536);
}

template<bool BIAS>
__device__ __forceinline__ f32x16 qk_tile(
    int kt, int lo, int hi, const u32x4 (&qf)[4],
    const unsigned short* qbias_lds,
    u32x4 k0, u32x4 k1, u32x4 k2, u32x4 k3) {
  f32x16 s = {};
  s = __builtin_amdgcn_mfma_f32_32x32x16_bf16(BC8(k0), BC8(qf[0]), s, 0, 0, 0);
  s = __builtin_amdgcn_mfma_f32_32x32x16_bf16(BC8(k1), BC8(qf[1]), s, 0, 0, 0);
  s = __builtin_amdgcn_mfma_f32_32x32x16_bf16(BC8(k2), BC8(qf[2]), s, 0, 0, 0);
  s = __builtin_amdgcn_mfma_f32_32x32x16_bf16(BC8(k3), BC8(qf[3]), s, 0, 0, 0);
  if (BIAS) {
    const int kr = kt * 32 + lo;
    const int t = (kr >= S_) ? 1 : 0;
    const int sk = kr - t * S_;
    const int x = sk / W_, y = sk - x * W_;
    const int p1 = t*56 + x;
    const int p2 = t*56 + 28 + y;
    const uint_ v1 = 0x3F80u << ((p1 & 1) << 4);
    const uint_ v2 = 0x3F80u << ((p2 & 1) << 4);
    const int g1 = p1 >> 3, g2 = p2 >> 3;
    const int w1 = (p1 >> 1) & 3, w2 = (p2 >> 1) & 3;
    #pragma unroll
    for (int c = 0; c < 7; ++c) {
      const int gg = 2*c + hi;
      u32x4 oh;
      oh.x = ((g1 == gg && w1 == 0) ? v1 : 0u) | ((g2 == gg && w2 == 0) ? v2 : 0u);
      oh.y = ((g1 == gg && w1 == 1) ? v1 : 0u) | ((g2 == gg && w2 == 1) ? v2 : 0u);
      oh.z = ((g1 == gg && w1 == 2) ? v1 : 0u) | ((g2 == gg && w2 == 2) ? v2 : 0u);
      oh.w = ((g1 == gg && w1 == 3) ? v1 : 0u) | ((g2 == gg && w2 == 3) ? v2 : 0u);
      const u32x4 qb = *(const u32x4*)(qbias_lds + c * 512);
      s = __builtin_amdgcn_mfma_f32_32x32x16_bf16(BC8(oh), BC8(qb), s, 0, 0, 0);
    }
  }
  return s;
}

__device__ __forceinline__ void sm_pv(
    const f32x16& s,
    u32x4 va, u32x4 vb, u32x4 vc, u32x4 vd,
    f32x16& acc0, f32x16& acc1, float& l_run) {
  uint_ pw0, pw1, pw2, pw3, pw4, pw5, pw6, pw7;
  {
    float a, b;
    a = exp2f(s[0]);  b = exp2f(s[1]);  l_run += a+b; pw0 = cvtpk(a,b);
    a = exp2f(s[2]);  b = exp2f(s[3]);  l_run += a+b; pw1 = cvtpk(a,b);
    a = exp2f(s[4]);  b = exp2f(s[5]);  l_run += a+b; pw2 = cvtpk(a,b);
    a = exp2f(s[6]);  b = exp2f(s[7]);  l_run += a+b; pw3 = cvtpk(a,b);
    a = exp2f(s[8]);  b = exp2f(s[9]);  l_run += a+b; pw4 = cvtpk(a,b);
    a = exp2f(s[10]); b = exp2f(s[11]); l_run += a+b; pw5 = cvtpk(a,b);
    a = exp2f(s[12]); b = exp2f(s[13]); l_run += a+b; pw6 = cvtpk(a,b);
    a = exp2f(s[14]); b = exp2f(s[15]); l_run += a+b; pw7 = cvtpk(a,b);
  }
  auto sA = __builtin_amdgcn_permlane32_swap(pw0, pw2, false, false);
  auto sB = __builtin_amdgcn_permlane32_swap(pw1, pw3, false, false);
  auto sC = __builtin_amdgcn_permlane32_swap(pw4, pw6, false, false);
  auto sD = __builtin_amdgcn_permlane32_swap(pw5, pw7, false, false);
  u32x4 pa0, pa1;
  pa0.x = sA[0]; pa0.y = sB[0]; pa0.z = sA[1]; pa0.w = sB[1];
  pa1.x = sC[0]; pa1.y = sD[0]; pa1.z = sC[1]; pa1.w = sD[1];

  acc0 = __builtin_amdgcn_mfma_f32_32x32x16_bf16(BC8(pa0), BC8(va), acc0, 0, 0, 0);
  acc0 = __builtin_amdgcn_mfma_f32_32x32x16_bf16(BC8(pa1), BC8(vb), acc0, 0, 0, 0);
  acc1 = __builtin_amdgcn_mfma_f32_32x32x16_bf16(BC8(pa0), BC8(vc), acc1, 0, 0, 0);
  acc1 = __builtin_amdgcn_mfma_f32_32x32x16_bf16(BC8(pa1), BC8(vd), acc1, 0, 0, 0);
}

__device__ __forceinline__ bool bias_needed(int kt, int qt) {
  const int kmin = (kt * 32 >= S_) ? 1 : 0;
  const int kmax = (kt * 32 + 31 >= S_) ? 1 : 0;
  const int qmin = (qt * 32 >= S_) ? 1 : 0;
  const int qmax = (qt * 32 + 31 >= S_) ? 1 : 0;
  return (kmin <= qmax) && (qmin <= kmax);
}

__global__ __launch_bounds__(256) void attn_mfma(
    const unsigned short* __restrict__ Qmain, const unsigned short* __restrict__ QbiasPack,
    const unsigned short* __restrict__ Kpack, const unsigned short* __restrict__ Vpack,
    unsigned short* __restrict__ Abf) {
  __shared__ float red_acc[3][32][64];
  __shared__ float red_l[4][32];
  __shared__ __align__(16) unsigned short qb_lds[3584];

  const int id0 = blockIdx.x;                  // 1176 = 8 * 147
  const int swz = (id0 & 7) * 147 + (id0 >> 3);
  const int qt = swz % 49;
  const int bh = swz / 49;

  const int lane = threadIdx.x & 63;
  const int wv = threadIdx.x >> 6;             // 0..3
  const int lo = lane & 31, hi = lane >> 5;
  const int q0 = qt * 32;

  {
    const unsigned short* src = QbiasPack + ((size_t)bh * 49 + qt) * 3584;
    for (int i = wv; i < 7; i += 4)
      gload16(src + i * 512 + lane * 8, qb_lds + i * 512);
  }

  const unsigned short* qrow = Qmain + ((size_t)bh * L_ + q0 + lo) * 64 + hi * 8;
  u32x4 qf[4];
  #pragma unroll
  for (int c = 0; c < 4; ++c) qf[c] = *(const u32x4*)(qrow + c * 16);
  const unsigned short* qbias_lds = qb_lds + lane * 8;

  const unsigned short* kbase = Kpack + (size_t)bh * 49 * 2048 + lane * 8;
  const unsigned short* vbase = Vpack + (size_t)bh * 49 * 2048 + lane * 8;

  f32x16 acc0 = {}, acc1 = {};
  float l_run = 0.f;
  const int nt = (49 - wv + 3) >> 2;           // wave wv: tiles kt = wv + 4*j

  __syncthreads();   // qb_lds ready

  #define KT(j) (wv + 4 * (j))
  #define QK(j, K0, K1, K2, K3) \
    (bias_needed(KT(j), qt) \
      ? qk_tile<true>(KT(j), lo, hi, qf, qbias_lds, K0, K1, K2, K3) \
      : qk_tile<false>(KT(j), lo, hi, qf, qbias_lds, K0, K1, K2, K3))

  u32x4 kA0, kA1, kA2, kA3, kB0, kB1, kB2, kB3;
  u32x4 va, vb, vc, vd;

  load_k(kbase, KT(0), kA0, kA1, kA2, kA3);
  load_k(kbase, KT(1), kB0, kB1, kB2, kB3);
  f32x16 s_prev = QK(0, kA0, kA1, kA2, kA3);

  int j = 1;
  for (; j + 1 < nt; j += 2) {
    load_v(vbase, KT(j - 1), va, vb, vc, vd);
    f32x16 s_cur = QK(j, kB0, kB1, kB2, kB3);
    load_k(kbase, KT(j + 1), kA0, kA1, kA2, kA3);
    sm_pv(s_prev, va, vb, vc, vd, acc0, acc1, l_run);
    s_prev = s_cur;
    load_v(vbase, KT(j), va, vb, vc, vd);
    f32x16 s_cur2 = QK(j + 1, kA0, kA1, kA2, kA3);
    const int pf = (j + 2 < nt) ? j + 2 : nt - 1;
    load_k(kbase, KT(pf), kB0, kB1, kB2, kB3);
    sm_pv(s_prev, va, vb, vc, vd, acc0, acc1, l_run);
    s_prev = s_cur2;
  }
  if (j < nt) {
    load_v(vbase, KT(j - 1), va, vb, vc, vd);
    f32x16 s_cur = QK(j, kB0, kB1, kB2, kB3);
    sm_pv(s_prev, va, vb, vc, vd, acc0, acc1, l_run);
    s_prev = s_cur;
  }
  load_v(vbase, KT(nt - 1), va, vb, vc, vd);
  sm_pv(s_prev, va, vb, vc, vd, acc0, acc1, l_run);
  #undef QK
  #undef KT

  l_run += __shfl_xor(l_run, 32);

  if (hi == 0) red_l[wv][lo] = l_run;
  if (wv >= 1) {
    #pragma unroll
    for (int r = 0; r < 16; ++r) {
      const int row = (r & 3) + 8*(r >> 2) + 4*hi;
      red_acc[wv-1][row][lo]      = acc0[r];
      red_acc[wv-1][row][32 + lo] = acc1[r];
    }
  }
  __syncthreads();
  if (wv == 0) {
    const int b = bh / NH_, h = bh % NH_;
    #pragma unroll
    for (int r = 0; r < 16; ++r) {
      const int row = (r & 3) + 8*(r >> 2) + 4*hi;
      const float inv = 1.0f / (red_l[0][row] + red_l[1][row] +
                                red_l[2][row] + red_l[3][row]);
      const float o0 = (acc0[r] + red_acc[0][row][lo] +
                        red_acc[1][row][lo] + red_acc[2][row][lo]) * inv;
      const float o1 = (acc1[r] + red_acc[0][row][32+lo] +
                        red_acc[1][row][32+lo] + red_acc[2][row][32+lo]) * inv;
      const size_t qoff = ((size_t)bh * L_ + q0 + row) * 64 + lo;
      const size_t ooff = ((size_t)(b * L_ + q0 + row)) * C_ + h * 64 + lo;
      Abf[ooff]      = f2bf(o0 + bf2f(Qmain[qoff]));
      Abf[ooff + 32] = f2bf(o1 + bf2f(Qmain[qoff + 32]));
    }
  }
}

// ---------------------------------------------------------------------------
extern "C" void kernel_launch(void* const* d_in, const int* in_sizes, int n_in,
                              void* d_out, int out_size, void* d_ws, size_t ws_size,
                              hipStream_t stream) {
  const float* x         = (const float*)d_in[0];
  const float* qkv_w     = (const float*)d_in[1];
  const float* out_w     = (const float*)d_in[2];
  const float* out_b     = (const float*)d_in[3];
  const float* q_pool_w  = (const float*)d_in[4];
  const float* k_pool_w  = (const float*)d_in[5];
  const float* v_pool_w  = (const float*)d_in[6];
  const float* q_ln_g    = (const float*)d_in[7];
  const float* q_ln_b    = (const float*)d_in[8];
  const float* k_ln_g    = (const float*)d_in[9];
  const float* k_ln_b    = (const float*)d_in[10];
  const float* v_ln_g    = (const float*)d_in[11];
  const float* v_ln_b    = (const float*)d_in[12];
  const float* rel_pos_h = (const float*)d_in[13];
  const float* rel_pos_w = (const float*)d_in[14];

  float* R = (float*)d_ws;
  const size_t NQ = (size_t)B_ * NH_ * L_ * HD_;   // 2,408,448 f32 slots
  unsigned short* q_raw = (unsigned short*)R;      // bf16
  unsigned short* Abf = (unsigned short*)R;        // alias (q_raw dead after pool)
  unsigned short* k_raw = (unsigned short*)(R + NQ);
  unsigned short* v_raw = (unsigned short*)(R + 2*NQ);
  const size_t D_off = 3*NQ;
  unsigned short* Xbf   = (unsigned short*)(R + D_off);
  unsigned short* Qmain = (unsigned short*)(R + D_off);
  const size_t E_off = D_off + 1228800;
  unsigned short* Kpack = (unsigned short*)(R + E_off);
  const size_t F_off = E_off + 1204224;
  unsigned short* Wbf   = (unsigned short*)(R + F_off);
  unsigned short* Vpack = (unsigned short*)(R + F_off);
  const size_t G_off = F_off + 1204224;
  unsigned short* Wobf = (unsigned short*)(R + G_off);
  const size_t H_off = G_off + 294912;
  unsigned short* QbiasPack = (unsigned short*)(R + H_off);
  const size_t I_off = H_off + 2107392;
  unsigned short* Rhb = (unsigned short*)(R + I_off);
  unsigned short* Rwb = (unsigned short*)(R + I_off + 2048);

  // x + qkv_w + out_w conversions fill blocks 0..2327 exactly;
  // blocks 2328..2331 handle the 8192 rel-table outputs.
  cvt_all<<<2332, 256, 0, stream>>>(x, 3136*768, Xbf,
                                    qkv_w, 2304*768, Wbf,
                                    out_w, 768*768, Wobf,
                                    rel_pos_h, rel_pos_w, Rhb, Rwb);
  qkv_gemm_mfma<<<dim3(36, 25), 256, 0, stream>>>(Xbf, Wbf, q_raw, k_raw, v_raw);
  pool_ln_fused<<<dim3(2352, 3), 256, 0, stream>>>(
      q_raw, k_raw, v_raw, q_pool_w, k_pool_w, v_pool_w,
      q_ln_g, q_ln_b, k_ln_g, k_ln_b, v_ln_g, v_ln_b, Qmain, Kpack, Vpack);
  relpos_mfma<<<dim3(49, 48), 64, 0, stream>>>(Qmain, Rhb, Rwb, QbiasPack);
  attn_mfma<<<1176, 256, 0, stream>>>(Qmain, QbiasPack, Kpack, Vpack, Abf);
  proj_gemm_mfma<<<dim3(12, 50), 256, 0, stream>>>(Abf, Wobf, out_b, (float*)d_out);
}

// Round 22
// 123.210 us; speedup vs baseline: 1.0108x; 1.0016x over previous
//
#include <hip/hip_runtime.h>
#include <math.h>

#define B_ 2
#define T_ 2
#define H_ 28
#define W_ 28
#define S_ (H_*W_)      /* 784  */
#define L_ (T_*S_)      /* 1568 */
#define C_ 768
#define NH_ 12
#define HD_ 64
#define LN_EPS 1e-5f
#define LOG2E 1.4426950408889634f
#define SCALE_K (0.125f * LOG2E)   /* hd^-0.5 * log2e folded into K' */

typedef unsigned int uint_;
typedef unsigned int u32x2 __attribute__((ext_vector_type(2)));
typedef unsigned int u32x4 __attribute__((ext_vector_type(4)));
typedef __bf16 bf16x8 __attribute__((ext_vector_type(8)));
typedef float f32x4 __attribute__((ext_vector_type(4)));
typedef float f32x16 __attribute__((ext_vector_type(16)));

#define BC8(x) __builtin_bit_cast(bf16x8, (x))

__device__ __forceinline__ unsigned short f2bf(float f) {
  uint_ u = __builtin_bit_cast(uint_, f);
  u += 0x7FFFu + ((u >> 16) & 1u);
  return (unsigned short)(u >> 16);
}
__device__ __forceinline__ float bf2f(unsigned short h) {
  return __builtin_bit_cast(float, ((uint_)h) << 16);
}
__device__ __forceinline__ uint_ cvtpk(float a, float b) {
  uint_ r;
  asm("v_cvt_pk_bf16_f32 %0, %1, %2" : "=v"(r) : "v"(a), "v"(b));
  return r;
}
__device__ __forceinline__ void gload16(const void* g, void* l) {
  __builtin_amdgcn_global_load_lds(
      (const __attribute__((address_space(1))) unsigned int*)g,
      (__attribute__((address_space(3))) unsigned int*)l, 16, 0, 0);
}

// ---------------------------------------------------------------------------
// Fused f32 -> bf16 convert: x / qkv_w / out_w, plus rel tables (LOG2E-scaled,
// zero-padded to [64][64]) as a 4th range. Blocks 0..2327 cover exactly
// (3136+2304+768)*768 = 4,767,744 elements; blocks 2328..2331 cover 8192 rel.
// ---------------------------------------------------------------------------
__global__ __launch_bounds__(256) void cvt_all(
    const float* __restrict__ s0, int n0, unsigned short* __restrict__ d0,
    const float* __restrict__ s1, int n1, unsigned short* __restrict__ d1,
    const float* __restrict__ s2, int n2, unsigned short* __restrict__ d2,
    const float* __restrict__ rph, const float* __restrict__ rpw,
    unsigned short* __restrict__ Rhb, unsigned short* __restrict__ Rwb) {
  int i = (blockIdx.x * 256 + threadIdx.x) * 8;
  const int ntot = n0 + n1 + n2;
  if (i >= ntot) {                     // rel-table segment: 8192 u16 outputs
    i -= ntot;
    if (i >= 8192) return;
    #pragma unroll
    for (int e = 0; e < 8; ++e) {
      const int o = i + e;
      const int idx = o & 4095;
      const int j = idx >> 6;
      const float* src = (o < 4096) ? rph : rpw;
      unsigned short* dst = (o < 4096) ? Rhb : Rwb;
      dst[idx] = (j < 2*H_-1) ? f2bf(src[idx] * LOG2E) : 0;
    }
    return;
  }
  const float* s; unsigned short* d;
  if (i < n0) { s = s0; d = d0; }
  else if (i < n0 + n1) { i -= n0; s = s1; d = d1; }
  else { i -= n0 + n1; s = s2; d = d2; }
  float4 a = *(const float4*)(s + i);
  float4 b = *(const float4*)(s + i + 4);
  u32x4 o;
  o.x = cvtpk(a.x, a.y); o.y = cvtpk(a.z, a.w);
  o.z = cvtpk(b.x, b.y); o.w = cvtpk(b.z, b.w);
  *(u32x4*)(d + i) = o;
}

// ---------------------------------------------------------------------------
// Templated bf16 MFMA GEMM core: C = A * B^T, BMxBN tile, BK=32, 4 waves
// (2x2), wave covers (BM/2)x(BN/2). Single-buffered LDS, 2 barriers/K-step.
// ---------------------------------------------------------------------------
template<int BM, int BN>
__device__ __forceinline__ void gemm_core_t(
    const unsigned short* __restrict__ A, const unsigned short* __restrict__ Bm,
    int K, int m0, int n0, f32x4 (&acc)[BM/32][BN/32]) {
  constexpr int MF = BM / 32;
  constexpr int NF = BN / 32;
  __shared__ __align__(16) unsigned short As[BM * 32];
  __shared__ __align__(16) unsigned short Bs[BN * 32];
  const int tid = threadIdx.x;
  const int lane = tid & 63;
  const int wv = tid >> 6;
  const int wm = wv >> 1, wn = wv & 1;
  const int srow = tid >> 2, scol = (tid & 3) * 8;
  const int fr = lane & 15, fk = (lane >> 4) * 8;
  const unsigned short* ag = A + (size_t)(m0 + srow) * K + scol;
  const unsigned short* bg = Bm + (size_t)(n0 + srow) * K + scol;
  unsigned short* asd = As + tid * 8;
  unsigned short* bsd = Bs + tid * 8;
  const int arow = wm * (BM / 2) + fr;
  const int brow = wn * (BN / 2) + fr;
  for (int k0 = 0; k0 < K; k0 += 32) {
    __syncthreads();
    #pragma unroll
    for (int r = 0; r < BM / 64; ++r)
      gload16(ag + (size_t)(r * 64) * K + k0, asd + r * 2048);
    #pragma unroll
    for (int r = 0; r < BN / 64; ++r)
      gload16(bg + (size_t)(r * 64) * K + k0, bsd + r * 2048);
    __syncthreads();
    bf16x8 af[MF], bfr[NF];
    #pragma unroll
    for (int m = 0; m < MF; ++m)
      af[m] = *(const bf16x8*)(As + (arow + m * 16) * 32 + fk);
    #pragma unroll
    for (int n = 0; n < NF; ++n)
      bfr[n] = *(const bf16x8*)(Bs + (brow + n * 16) * 32 + fk);
    #pragma unroll
    for (int m = 0; m < MF; ++m)
      #pragma unroll
      for (int n = 0; n < NF; ++n)
        acc[m][n] = __builtin_amdgcn_mfma_f32_16x16x32_bf16(af[m], bfr[n], acc[m][n], 0, 0, 0);
  }
}

// ---------------------------------------------------------------------------
// QKV GEMM: 128x64 tiles, grid (36,25)=900 blocks. Scatter bf16 q/k/v.
// m-guard REQUIRED: pad rows (gm>=3136) would wrap into head h+1 rows of b=1.
// ---------------------------------------------------------------------------
__global__ __launch_bounds__(256) void qkv_gemm_mfma(
    const unsigned short* __restrict__ Xbf, const unsigned short* __restrict__ Wbf,
    unsigned short* __restrict__ q_raw, unsigned short* __restrict__ k_raw,
    unsigned short* __restrict__ v_raw) {
  f32x4 acc[4][2] = {};
  const int m0 = blockIdx.y * 128;
  const int n0 = blockIdx.x * 64;
  gemm_core_t<128, 64>(Xbf, Wbf, C_, m0, n0, acc);
  const int lane = threadIdx.x & 63;
  const int wv = threadIdx.x >> 6;
  const int wm = wv >> 1, wn = wv & 1;
  const int fr = lane & 15, fj = (lane >> 4) * 4;
  const int which = (n0 >= 2 * C_) ? 2 : ((n0 >= C_) ? 1 : 0);
  const int h = (n0 - which * C_) >> 6;
  unsigned short* dst = (which == 0) ? q_raw : ((which == 1) ? k_raw : v_raw);
  #pragma unroll
  for (int n = 0; n < 2; ++n) {
    const int d = wn * 32 + n * 16 + fr;
    #pragma unroll
    for (int m = 0; m < 4; ++m) {
      #pragma unroll
      for (int j = 0; j < 4; ++j) {
        const int gm = m0 + wm * 64 + m * 16 + fj + j;
        if (gm < B_ * L_) {
          const int b = (gm >= L_) ? 1 : 0;
          const int l = gm - b * L_;
          dst[(((size_t)b * NH_ + h) * L_ + l) * HD_ + d] = f2bf(acc[m][n][j]);
        }
      }
    }
  }
}

// ---------------------------------------------------------------------------
// Proj GEMM: 64x64 tiles, grid (12,49)=588 blocks (49*64 = 3136 = B*L exactly;
// the former y=49 block row was 100% guarded-out dead work). + bias -> f32.
// ---------------------------------------------------------------------------
__global__ __launch_bounds__(256) void proj_gemm_mfma(
    const unsigned short* __restrict__ Abf, const unsigned short* __restrict__ Wobf,
    const float* __restrict__ bo, float* __restrict__ out) {
  f32x4 acc[2][2] = {};
  const int m0 = blockIdx.y * 64;
  const int n0 = blockIdx.x * 64;
  gemm_core_t<64, 64>(Abf, Wobf, C_, m0, n0, acc);
  const int lane = threadIdx.x & 63;
  const int wv = threadIdx.x >> 6;
  const int wm = wv >> 1, wn = wv & 1;
  const int fr = lane & 15, fj = (lane >> 4) * 4;
  #pragma unroll
  for (int n = 0; n < 2; ++n) {
    const int gn = n0 + wn * 32 + n * 16 + fr;
    const float bias = bo[gn];
    #pragma unroll
    for (int m = 0; m < 2; ++m) {
      #pragma unroll
      for (int j = 0; j < 4; ++j) {
        const int gm = m0 + wm * 32 + m * 16 + fj + j;
        if (gm < B_ * L_) out[(size_t)gm * C_ + gn] = acc[m][n][j] + bias;
      }
    }
  }
}

// ---------------------------------------------------------------------------
// Fused depthwise 3x3 conv + LayerNorm(64), FOUR rows per wave; bf16 inputs.
// ---------------------------------------------------------------------------
__global__ __launch_bounds__(256) void pool_ln_fused(
    const unsigned short* __restrict__ q_raw, const unsigned short* __restrict__ k_raw,
    const unsigned short* __restrict__ v_raw,
    const float* __restrict__ qw, const float* __restrict__ kw,
    const float* __restrict__ vw,
    const float* __restrict__ qg, const float* __restrict__ qb2,
    const float* __restrict__ kg, const float* __restrict__ kb2,
    const float* __restrict__ vg, const float* __restrict__ vb2,
    unsigned short* __restrict__ Qmain, unsigned short* __restrict__ Kpack,
    unsigned short* __restrict__ Vpack) {
  const int which = blockIdx.y;
  const unsigned short* in = (which == 0) ? q_raw : (which == 1) ? k_raw : v_raw;
  const float* w  = (which == 0) ? qw : (which == 1) ? kw : vw;
  const float* g  = (which == 0) ? qg : (which == 1) ? kg : vg;
  const float* bb = (which == 0) ? qb2 : (which == 1) ? kb2 : vb2;
  const float scale = (which == 1) ? SCALE_K : 1.f;

  const int quad = blockIdx.x * 4 + (threadIdx.x >> 6);  // 0..9407
  const int d = threadIdx.x & 63;
  const int row0 = quad * 4;
  const int bh = row0 / L_;
  const int l0  = row0 % L_;           // multiple of 4
  const int t  = l0 / S_;
  const int sq = l0 % S_;
  const int x = sq / W_, y = sq % W_;  // y multiple of 4
  const unsigned short* base = in + ((size_t)bh * L_ + t * S_) * HD_ + d;

  float acc0 = 0.f, acc1 = 0.f, acc2 = 0.f, acc3 = 0.f;
  #pragma unroll
  for (int dx = 0; dx < 3; ++dx) {
    const int xx = x + dx - 1;
    if (xx < 0 || xx >= H_) continue;
    const unsigned short* rb = base + (size_t)xx * W_ * HD_;
    const float w0 = w[(dx*3 + 0) * HD_ + d];
    const float w1 = w[(dx*3 + 1) * HD_ + d];
    const float w2 = w[(dx*3 + 2) * HD_ + d];
    const float cm1 = (y > 0)     ? bf2f(rb[(y-1) * HD_]) : 0.f;
    const float c0  = bf2f(rb[(y+0) * HD_]);
    const float c1  = bf2f(rb[(y+1) * HD_]);
    const float c2  = bf2f(rb[(y+2) * HD_]);
    const float c3  = bf2f(rb[(y+3) * HD_]);
    const float c4  = (y+4 < W_)  ? bf2f(rb[(y+4) * HD_]) : 0.f;
    acc0 += cm1*w0 + c0*w1 + c1*w2;
    acc1 += c0*w0  + c1*w1 + c2*w2;
    acc2 += c1*w0  + c2*w1 + c3*w2;
    acc3 += c2*w0  + c3*w1 + c4*w2;
  }
  float s0a = acc0, s0b = acc0*acc0, s1a = acc1, s1b = acc1*acc1;
  float s2a = acc2, s2b = acc2*acc2, s3a = acc3, s3b = acc3*acc3;
  #pragma unroll
  for (int off = 32; off; off >>= 1) {
    s0a += __shfl_xor(s0a, off); s0b += __shfl_xor(s0b, off);
    s1a += __shfl_xor(s1a, off); s1b += __shfl_xor(s1b, off);
    s2a += __shfl_xor(s2a, off); s2b += __shfl_xor(s2b, off);
    s3a += __shfl_xor(s3a, off); s3b += __shfl_xor(s3b, off);
  }
  const float gd = g[d], bd = bb[d];
  const float mu0 = s0a * (1.f/64.f), var0 = s0b * (1.f/64.f) - mu0*mu0;
  const float mu1 = s1a * (1.f/64.f), var1 = s1b * (1.f/64.f) - mu1*mu1;
  const float mu2 = s2a * (1.f/64.f), var2 = s2b * (1.f/64.f) - mu2*mu2;
  const float mu3 = s3a * (1.f/64.f), var3 = s3b * (1.f/64.f) - mu3*mu3;
  const float f0 = ((acc0 - mu0) * rsqrtf(var0 + LN_EPS) * gd + bd) * scale;
  const float f1 = ((acc1 - mu1) * rsqrtf(var1 + LN_EPS) * gd + bd) * scale;
  const float f2 = ((acc2 - mu2) * rsqrtf(var2 + LN_EPS) * gd + bd) * scale;
  const float f3 = ((acc3 - mu3) * rsqrtf(var3 + LN_EPS) * gd + bd) * scale;

  if (which == 1) {
    const unsigned short v0 = f2bf(f0), v1 = f2bf(f1);
    const unsigned short v2 = f2bf(f2), v3 = f2bf(f3);
    const int kt = l0 >> 5;
    const int c = d >> 4;
    const int lane2 = (((d >> 3) & 1) << 5) | (l0 & 31);
    unsigned short* kp = Kpack + ((((size_t)bh * 49 + kt) * 4 + c) * 64 + lane2) * 8 + (d & 7);
    kp[0] = v0; kp[8] = v1; kp[16] = v2; kp[24] = v3;
  } else if (which == 0) {
    Qmain[(size_t)(row0 + 0) * 64 + d] = f2bf(f0);
    Qmain[(size_t)(row0 + 1) * 64 + d] = f2bf(f1);
    Qmain[(size_t)(row0 + 2) * 64 + d] = f2bf(f2);
    Qmain[(size_t)(row0 + 3) * 64 + d] = f2bf(f3);
  } else {
    const int kt = l0 >> 5;
    const int c = ((d >> 5) << 1) | ((l0 >> 4) & 1);
    const int lane2 = (((l0 >> 3) & 1) << 5) | (d & 31);
    const int e = l0 & 7;   // 0 or 4
    u32x2 ov;
    ov.x = cvtpk(f0, f1);
    ov.y = cvtpk(f2, f3);
    *(u32x2*)(Vpack + ((((size_t)bh * 49 + kt) * 4 + c) * 64 + lane2) * 8 + e) = ov;
  }
}

// ---------------------------------------------------------------------------
// rel-pos via MFMA: P_h = Q*Rhb^T, P_w = Q*Rwb^T; bias rows are contiguous
// reversed slices of P. Writes QbiasPack fragment-order (incl. zero T-block).
// ---------------------------------------------------------------------------
__global__ __launch_bounds__(64) void relpos_mfma(
    const unsigned short* __restrict__ Qmain,
    const unsigned short* __restrict__ Rhb,
    const unsigned short* __restrict__ Rwb,
    unsigned short* __restrict__ QbiasPack) {
  __shared__ float P[16][128];
  const int qt16 = blockIdx.x;        // 0..48
  const int bt = blockIdx.y;          // 0..47
  const int bh = bt >> 1, t = bt & 1;
  const int lane = threadIdx.x;
  const int fr = lane & 15, fk = (lane >> 4) * 8;

  const size_t rowbase = (size_t)bh * L_ + t * S_ + qt16 * 16;
  const unsigned short* arow = Qmain + (rowbase + fr) * 64 + fk;
  const bf16x8 a0 = *(const bf16x8*)(arow);
  const bf16x8 a1 = *(const bf16x8*)(arow + 32);

  f32x4 acch[4] = {}, accw[4] = {};
  #pragma unroll
  for (int n = 0; n < 4; ++n) {
    const unsigned short* bh_ = Rhb + (n * 16 + fr) * 64 + fk;
    const unsigned short* bw_ = Rwb + (n * 16 + fr) * 64 + fk;
    acch[n] = __builtin_amdgcn_mfma_f32_16x16x32_bf16(a0, *(const bf16x8*)bh_, acch[n], 0, 0, 0);
    acch[n] = __builtin_amdgcn_mfma_f32_16x16x32_bf16(a1, *(const bf16x8*)(bh_ + 32), acch[n], 0, 0, 0);
    accw[n] = __builtin_amdgcn_mfma_f32_16x16x32_bf16(a0, *(const bf16x8*)bw_, accw[n], 0, 0, 0);
    accw[n] = __builtin_amdgcn_mfma_f32_16x16x32_bf16(a1, *(const bf16x8*)(bw_ + 32), accw[n], 0, 0, 0);
  }
  #pragma unroll
  for (int n = 0; n < 4; ++n)
    #pragma unroll
    for (int j = 0; j < 4; ++j) {
      P[(lane >> 4) * 4 + j][n * 16 + fr]      = acch[n][j];
      P[(lane >> 4) * 4 + j][64 + n * 16 + fr] = accw[n][j];
    }
  __syncthreads();

  if (lane < 56) {
    const int e0 = lane * 2;          // bias element pair
    const int tb = e0 / 56;
    const int tw0 = e0 % 56;
    const int cb = e0 >> 4;
    const int hi2 = (e0 >> 3) & 1;
    const int ee = e0 & 7;
    #pragma unroll
    for (int r = 0; r < 16; ++r) {
      const int gl = t * S_ + qt16 * 16 + r;
      const int sq = qt16 * 16 + r;
      const int x = sq / W_, y = sq % W_;
      float v0 = 0.f, v1 = 0.f;
      if (tb == t) {
        if (tw0 < 28) {
          v0 = P[r][x - tw0 + 27];
          v1 = P[r][x - tw0 + 26];
        } else {
          const int k0 = tw0 - 28;
          v0 = P[r][64 + y - k0 + 27];
          v1 = P[r][64 + y - k0 + 26];
        }
      }
      const int lane2 = (hi2 << 5) | (gl & 31);
      unsigned short* dst = QbiasPack +
          ((((size_t)bh * 49 + (gl >> 5)) * 7 + cb) * 64 + lane2) * 8 + ee;
      *(uint_*)dst = cvtpk(v0, v1);
    }
  }
}

// ---------------------------------------------------------------------------
// MFMA flash attention. 256 thr (4 waves), grid 1176 (XCD-swizzled).
// qbias staged in LDS (block-constant); fragment-packed K/V; fixed-base SM.
// ---------------------------------------------------------------------------
__device__ __forceinline__ void load_k(
    const unsigned short* kbase, int kt,
    u32x4& k0, u32x4& k1, u32x4& k2, u32x4& k3) {
  const unsigned short* kp = kbase + (size_t)kt * 2048;
  k0 = *(const u32x4*)(kp);
  k1 = *(const u32x4*)(kp + 512);
  k2 = *(const u32x4*)(kp + 1024);
  k3 = *(const u32x4*)(kp + 1536);
}

__device__ __forceinline__ void load_v(
    const unsigned short* vbase, int kt,
    u32x4& va, u32x4& vb, u32x4& vc, u32x4& vd) {
  const unsigned short* vp = vbase + (size_t)kt * 2048;
  va = *(const u32x4*)(vp);
  vb = *(const u32x4*)(vp + 512);
  vc = *(const u32x4*)(vp + 1024);
  vd = *(const u32x4*)(vp + 1536);
}

template<bool BIAS>
__device__ __forceinline__ f32x16 qk_tile(
    int kt, int lo, int hi, const u32x4 (&qf)[4],
    const unsigned short* qbias_lds,
    u32x4 k0, u32x4 k1, u32x4 k2, u32x4 k3) {
  f32x16 s = {};
  s = __builtin_amdgcn_mfma_f32_32x32x16_bf16(BC8(k0), BC8(qf[0]), s, 0, 0, 0);
  s = __builtin_amdgcn_mfma_f32_32x32x16_bf16(BC8(k1), BC8(qf[1]), s, 0, 0, 0);
  s = __builtin_amdgcn_mfma_f32_32x32x16_bf16(BC8(k2), BC8(qf[2]), s, 0, 0, 0);
  s = __builtin_amdgcn_mfma_f32_32x32x16_bf16(BC8(k3), BC8(qf[3]), s, 0, 0, 0);
  if (BIAS) {
    const int kr = kt * 32 + lo;
    const int t = (kr >= S_) ? 1 : 0;
    const int sk = kr - t * S_;
    const int x = sk / W_, y = sk - x * W_;
    const int p1 = t*56 + x;
    const int p2 = t*56 + 28 + y;
    const uint_ v1 = 0x3F80u << ((p1 & 1) << 4);
    const uint_ v2 = 0x3F80u << ((p2 & 1) << 4);
    const int g1 = p1 >> 3, g2 = p2 >> 3;
    const int w1 = (p1 >> 1) & 3, w2 = (p2 >> 1) & 3;
    #pragma unroll
    for (int c = 0; c < 7; ++c) {
      const int gg = 2*c + hi;
      u32x4 oh;
      oh.x = ((g1 == gg && w1 == 0) ? v1 : 0u) | ((g2 == gg && w2 == 0) ? v2 : 0u);
      oh.y = ((g1 == gg && w1 == 1) ? v1 : 0u) | ((g2 == gg && w2 == 1) ? v2 : 0u);
      oh.z = ((g1 == gg && w1 == 2) ? v1 : 0u) | ((g2 == gg && w2 == 2) ? v2 : 0u);
      oh.w = ((g1 == gg && w1 == 3) ? v1 : 0u) | ((g2 == gg && w2 == 3) ? v2 : 0u);
      const u32x4 qb = *(const u32x4*)(qbias_lds + c * 512);
      s = __builtin_amdgcn_mfma_f32_32x32x16_bf16(BC8(oh), BC8(qb), s, 0, 0, 0);
    }
  }
  return s;
}

__device__ __forceinline__ void sm_pv(
    const f32x16& s,
    u32x4 va, u32x4 vb, u32x4 vc, u32x4 vd,
    f32x16& acc0, f32x16& acc1, float& l_run) {
  uint_ pw0, pw1, pw2, pw3, pw4, pw5, pw6, pw7;
  {
    float a, b;
    a = exp2f(s[0]);  b = exp2f(s[1]);  l_run += a+b; pw0 = cvtpk(a,b);
    a = exp2f(s[2]);  b = exp2f(s[3]);  l_run += a+b; pw1 = cvtpk(a,b);
    a = exp2f(s[4]);  b = exp2f(s[5]);  l_run += a+b; pw2 = cvtpk(a,b);
    a = exp2f(s[6]);  b = exp2f(s[7]);  l_run += a+b; pw3 = cvtpk(a,b);
    a = exp2f(s[8]);  b = exp2f(s[9]);  l_run += a+b; pw4 = cvtpk(a,b);
    a = exp2f(s[10]); b = exp2f(s[11]); l_run += a+b; pw5 = cvtpk(a,b);
    a = exp2f(s[12]); b = exp2f(s[13]); l_run += a+b; pw6 = cvtpk(a,b);
    a = exp2f(s[14]); b = exp2f(s[15]); l_run += a+b; pw7 = cvtpk(a,b);
  }
  auto sA = __builtin_amdgcn_permlane32_swap(pw0, pw2, false, false);
  auto sB = __builtin_amdgcn_permlane32_swap(pw1, pw3, false, false);
  auto sC = __builtin_amdgcn_permlane32_swap(pw4, pw6, false, false);
  auto sD = __builtin_amdgcn_permlane32_swap(pw5, pw7, false, false);
  u32x4 pa0, pa1;
  pa0.x = sA[0]; pa0.y = sB[0]; pa0.z = sA[1]; pa0.w = sB[1];
  pa1.x = sC[0]; pa1.y = sD[0]; pa1.z = sC[1]; pa1.w = sD[1];

  acc0 = __builtin_amdgcn_mfma_f32_32x32x16_bf16(BC8(pa0), BC8(va), acc0, 0, 0, 0);
  acc0 = __builtin_amdgcn_mfma_f32_32x32x16_bf16(BC8(pa1), BC8(vb), acc0, 0, 0, 0);
  acc1 = __builtin_amdgcn_mfma_f32_32x32x16_bf16(BC8(pa0), BC8(vc), acc1, 0, 0, 0);
  acc1 = __builtin_amdgcn_mfma_f32_32x32x16_bf16(BC8(pa1), BC8(vd), acc1, 0, 0, 0);
}

__device__ __forceinline__ bool bias_needed(int kt, int qt) {
  const int kmin = (kt * 32 >= S_) ? 1 : 0;
  const int kmax = (kt * 32 + 31 >= S_) ? 1 : 0;
  const int qmin = (qt * 32 >= S_) ? 1 : 0;
  const int qmax = (qt * 32 + 31 >= S_) ? 1 : 0;
  return (kmin <= qmax) && (qmin <= kmax);
}

__global__ __launch_bounds__(256) void attn_mfma(
    const unsigned short* __restrict__ Qmain, const unsigned short* __restrict__ QbiasPack,
    const unsigned short* __restrict__ Kpack, const unsigned short* __restrict__ Vpack,
    unsigned short* __restrict__ Abf) {
  __shared__ float red_acc[3][32][64];
  __shared__ float red_l[4][32];
  __shared__ __align__(16) unsigned short qb_lds[3584];

  const int id0 = blockIdx.x;                  // 1176 = 8 * 147
  const int swz = (id0 & 7) * 147 + (id0 >> 3);
  const int qt = swz % 49;
  const int bh = swz / 49;

  const int lane = threadIdx.x & 63;
  const int wv = threadIdx.x >> 6;             // 0..3
  const int lo = lane & 31, hi = lane >> 5;
  const int q0 = qt * 32;

  {
    const unsigned short* src = QbiasPack + ((size_t)bh * 49 + qt) * 3584;
    for (int i = wv; i < 7; i += 4)
      gload16(src + i * 512 + lane * 8, qb_lds + i * 512);
  }

  const unsigned short* qrow = Qmain + ((size_t)bh * L_ + q0 + lo) * 64 + hi * 8;
  u32x4 qf[4];
  #pragma unroll
  for (int c = 0; c < 4; ++c) qf[c] = *(const u32x4*)(qrow + c * 16);
  const unsigned short* qbias_lds = qb_lds + lane * 8;

  const unsigned short* kbase = Kpack + (size_t)bh * 49 * 2048 + lane * 8;
  const unsigned short* vbase = Vpack + (size_t)bh * 49 * 2048 + lane * 8;

  f32x16 acc0 = {}, acc1 = {};
  float l_run = 0.f;
  const int nt = (49 - wv + 3) >> 2;           // wave wv: tiles kt = wv + 4*j

  __syncthreads();   // qb_lds ready

  #define KT(j) (wv + 4 * (j))
  #define QK(j, K0, K1, K2, K3) \
    (bias_needed(KT(j), qt) \
      ? qk_tile<true>(KT(j), lo, hi, qf, qbias_lds, K0, K1, K2, K3) \
      : qk_tile<false>(KT(j), lo, hi, qf, qbias_lds, K0, K1, K2, K3))

  u32x4 kA0, kA1, kA2, kA3, kB0, kB1, kB2, kB3;
  u32x4 va, vb, vc, vd;

  load_k(kbase, KT(0), kA0, kA1, kA2, kA3);
  load_k(kbase, KT(1), kB0, kB1, kB2, kB3);
  f32x16 s_prev = QK(0, kA0, kA1, kA2, kA3);

  int j = 1;
  for (; j + 1 < nt; j += 2) {
    load_v(vbase, KT(j - 1), va, vb, vc, vd);
    f32x16 s_cur = QK(j, kB0, kB1, kB2, kB3);
    load_k(kbase, KT(j + 1), kA0, kA1, kA2, kA3);
    sm_pv(s_prev, va, vb, vc, vd, acc0, acc1, l_run);
    s_prev = s_cur;
    load_v(vbase, KT(j), va, vb, vc, vd);
    f32x16 s_cur2 = QK(j + 1, kA0, kA1, kA2, kA3);
    const int pf = (j + 2 < nt) ? j + 2 : nt - 1;
    load_k(kbase, KT(pf), kB0, kB1, kB2, kB3);
    sm_pv(s_prev, va, vb, vc, vd, acc0, acc1, l_run);
    s_prev = s_cur2;
  }
  if (j < nt) {
    load_v(vbase, KT(j - 1), va, vb, vc, vd);
    f32x16 s_cur = QK(j, kB0, kB1, kB2, kB3);
    sm_pv(s_prev, va, vb, vc, vd, acc0, acc1, l_run);
    s_prev = s_cur;
  }
  load_v(vbase, KT(nt - 1), va, vb, vc, vd);
  sm_pv(s_prev, va, vb, vc, vd, acc0, acc1, l_run);
  #undef QK
  #undef KT

  l_run += __shfl_xor(l_run, 32);

  if (hi == 0) red_l[wv][lo] = l_run;
  if (wv >= 1) {
    #pragma unroll
    for (int r = 0; r < 16; ++r) {
      const int row = (r & 3) + 8*(r >> 2) + 4*hi;
      red_acc[wv-1][row][lo]      = acc0[r];
      red_acc[wv-1][row][32 + lo] = acc1[r];
    }
  }
  __syncthreads();
  if (wv == 0) {
    const int b = bh / NH_, h = bh % NH_;
    #pragma unroll
    for (int r = 0; r < 16; ++r) {
      const int row = (r & 3) + 8*(r >> 2) + 4*hi;
      const float inv = 1.0f / (red_l[0][row] + red_l[1][row] +
                                red_l[2][row] + red_l[3][row]);
      const float o0 = (acc0[r] + red_acc[0][row][lo] +
                        red_acc[1][row][lo] + red_acc[2][row][lo]) * inv;
      const float o1 = (acc1[r] + red_acc[0][row][32+lo] +
                        red_acc[1][row][32+lo] + red_acc[2][row][32+lo]) * inv;
      const size_t qoff = ((size_t)bh * L_ + q0 + row) * 64 + lo;
      const size_t ooff = ((size_t)(b * L_ + q0 + row)) * C_ + h * 64 + lo;
      Abf[ooff]      = f2bf(o0 + bf2f(Qmain[qoff]));
      Abf[ooff + 32] = f2bf(o1 + bf2f(Qmain[qoff + 32]));
    }
  }
}

// ---------------------------------------------------------------------------
extern "C" void kernel_launch(void* const* d_in, const int* in_sizes, int n_in,
                              void* d_out, int out_size, void* d_ws, size_t ws_size,
                              hipStream_t stream) {
  const float* x         = (const float*)d_in[0];
  const float* qkv_w     = (const float*)d_in[1];
  const float* out_w     = (const float*)d_in[2];
  const float* out_b     = (const float*)d_in[3];
  const float* q_pool_w  = (const float*)d_in[4];
  const float* k_pool_w  = (const float*)d_in[5];
  const float* v_pool_w  = (const float*)d_in[6];
  const float* q_ln_g    = (const float*)d_in[7];
  const float* q_ln_b    = (const float*)d_in[8];
  const float* k_ln_g    = (const float*)d_in[9];
  const float* k_ln_b    = (const float*)d_in[10];
  const float* v_ln_g    = (const float*)d_in[11];
  const float* v_ln_b    = (const float*)d_in[12];
  const float* rel_pos_h = (const float*)d_in[13];
  const float* rel_pos_w = (const float*)d_in[14];

  float* R = (float*)d_ws;
  const size_t NQ = (size_t)B_ * NH_ * L_ * HD_;   // 2,408,448 f32 slots
  unsigned short* q_raw = (unsigned short*)R;      // bf16
  unsigned short* Abf = (unsigned short*)R;        // alias (q_raw dead after pool)
  unsigned short* k_raw = (unsigned short*)(R + NQ);
  unsigned short* v_raw = (unsigned short*)(R + 2*NQ);
  const size_t D_off = 3*NQ;
  unsigned short* Xbf   = (unsigned short*)(R + D_off);
  unsigned short* Qmain = (unsigned short*)(R + D_off);
  const size_t E_off = D_off + 1228800;
  unsigned short* Kpack = (unsigned short*)(R + E_off);
  const size_t F_off = E_off + 1204224;
  unsigned short* Wbf   = (unsigned short*)(R + F_off);
  unsigned short* Vpack = (unsigned short*)(R + F_off);
  const size_t G_off = F_off + 1204224;
  unsigned short* Wobf = (unsigned short*)(R + G_off);
  const size_t H_off = G_off + 294912;
  unsigned short* QbiasPack = (unsigned short*)(R + H_off);
  const size_t I_off = H_off + 2107392;
  unsigned short* Rhb = (unsigned short*)(R + I_off);
  unsigned short* Rwb = (unsigned short*)(R + I_off + 2048);

  cvt_all<<<2332, 256, 0, stream>>>(x, 3136*768, Xbf,
                                    qkv_w, 2304*768, Wbf,
                                    out_w, 768*768, Wobf,
                                    rel_pos_h, rel_pos_w, Rhb, Rwb);
  qkv_gemm_mfma<<<dim3(36, 25), 256, 0, stream>>>(Xbf, Wbf, q_raw, k_raw, v_raw);
  pool_ln_fused<<<dim3(2352, 3), 256, 0, stream>>>(
      q_raw, k_raw, v_raw, q_pool_w, k_pool_w, v_pool_w,
      q_ln_g, q_ln_b, k_ln_g, k_ln_b, v_ln_g, v_ln_b, Qmain, Kpack, Vpack);
  relpos_mfma<<<dim3(49, 48), 64, 0, stream>>>(Qmain, Rhb, Rwb, QbiasPack);
  attn_mfma<<<1176, 256, 0, stream>>>(Qmain, QbiasPack, Kpack, Vpack, Abf);
  proj_gemm_mfma<<<dim3(12, 49), 256, 0, stream>>>(Abf, Wobf, out_b, (float*)d_out);
}